// Round 1
// baseline (4367.497 us; speedup 1.0000x reference)
//
#include <hip/hip_runtime.h>
#include <math.h>

#define B_ 8
#define T_ 1024
#define C_ 768
#define H_ 12
#define D_ 64

// C[M,N] = A[M,K] @ B[K,N] + bias[N]   (row-major, fp32, 64x64 tile, KT=16)
__global__ __launch_bounds__(256)
void gemm_bias(const float* __restrict__ A, const float* __restrict__ Bm,
               const float* __restrict__ bias, float* __restrict__ Cm,
               int M, int N, int K) {
    __shared__ float As[16][65];
    __shared__ float Bs[16][65];
    const int tid = threadIdx.x;
    const int tx = tid & 15;        // 16 thread-cols
    const int ty = tid >> 4;        // 16 thread-rows
    const int bm = blockIdx.y * 64;
    const int bn = blockIdx.x * 64;

    float acc[4][4];
#pragma unroll
    for (int i = 0; i < 4; i++)
#pragma unroll
        for (int j = 0; j < 4; j++) acc[i][j] = 0.f;

    for (int k0 = 0; k0 < K; k0 += 16) {
        // A tile: 64 rows x 16 k   (consecutive tid -> consecutive k)
#pragma unroll
        for (int i = tid; i < 64 * 16; i += 256) {
            int mm = i >> 4;
            int kk = i & 15;
            As[kk][mm] = A[(size_t)(bm + mm) * K + k0 + kk];
        }
        // B tile: 16 k x 64 cols   (consecutive tid -> consecutive n, coalesced)
#pragma unroll
        for (int i = tid; i < 16 * 64; i += 256) {
            int kk = i >> 6;
            int nn = i & 63;
            Bs[kk][nn] = Bm[(size_t)(k0 + kk) * N + bn + nn];
        }
        __syncthreads();
#pragma unroll
        for (int kk = 0; kk < 16; kk++) {
            float a[4], bv[4];
#pragma unroll
            for (int i = 0; i < 4; i++) a[i] = As[kk][ty * 4 + i];
#pragma unroll
            for (int j = 0; j < 4; j++) bv[j] = Bs[kk][tx * 4 + j];
#pragma unroll
            for (int i = 0; i < 4; i++)
#pragma unroll
                for (int j = 0; j < 4; j++) acc[i][j] += a[i] * bv[j];
        }
        __syncthreads();
    }
#pragma unroll
    for (int i = 0; i < 4; i++) {
        int row = bm + ty * 4 + i;
#pragma unroll
        for (int j = 0; j < 4; j++) {
            int col = bn + tx * 4 + j;
            Cm[(size_t)row * N + col] = acc[i][j] + bias[col];
        }
    }
}

// One wave (64 lanes) per (b,h,q) row. lane = d. Online softmax over k<=q.
__global__ __launch_bounds__(64)
void attn(const float* __restrict__ qkv, float* __restrict__ y) {
    const int lane = threadIdx.x;          // d index, 0..63
    const int q    = blockIdx.x;           // 0..T-1
    const int bh   = blockIdx.y;           // 0..B*H-1
    const int b    = bh / H_;
    const int h    = bh % H_;
    const size_t row3C = 3 * C_;

    const float qv = qkv[((size_t)(b * T_ + q)) * row3C + h * D_ + lane] * 0.125f;
    const float* kbase = qkv + (size_t)b * T_ * row3C + C_ + h * D_;
    const float* vbase = qkv + (size_t)b * T_ * row3C + 2 * C_ + h * D_;

    float m = -INFINITY, l = 0.f, o = 0.f;
    for (int k = 0; k <= q; k++) {
        float kv = kbase[(size_t)k * row3C + lane];
        float vv = vbase[(size_t)k * row3C + lane];
        float s = qv * kv;
#pragma unroll
        for (int off = 32; off > 0; off >>= 1) s += __shfl_xor(s, off, 64);
        float mn    = fmaxf(m, s);
        float alpha = __expf(m - mn);   // m=-inf first iter -> 0
        float p     = __expf(s - mn);
        l = l * alpha + p;
        o = o * alpha + p * vv;
        m = mn;
    }
    y[((size_t)(b * T_ + q)) * C_ + h * D_ + lane] = o / l;
}

extern "C" void kernel_launch(void* const* d_in, const int* in_sizes, int n_in,
                              void* d_out, int out_size, void* d_ws, size_t ws_size,
                              hipStream_t stream) {
    const float* x      = (const float*)d_in[0];
    const float* w_qkv  = (const float*)d_in[1];
    const float* b_qkv  = (const float*)d_in[2];
    const float* w_proj = (const float*)d_in[3];
    const float* b_proj = (const float*)d_in[4];
    float* out = (float*)d_out;

    float* qkv = (float*)d_ws;                       // [B*T, 3C]
    float* y   = qkv + (size_t)B_ * T_ * 3 * C_;     // [B*T, C]

    // 1) qkv = x @ w_qkv + b_qkv       M=8192 N=2304 K=768
    dim3 g1(3 * C_ / 64, B_ * T_ / 64);
    gemm_bias<<<g1, 256, 0, stream>>>(x, w_qkv, b_qkv, qkv, B_ * T_, 3 * C_, C_);

    // 2) attention -> y [B*T, C]
    dim3 g2(T_, B_ * H_);
    attn<<<g2, 64, 0, stream>>>(qkv, y);

    // 3) out = y @ w_proj + b_proj     M=8192 N=768 K=768
    dim3 g3(C_ / 64, B_ * T_ / 64);
    gemm_bias<<<g3, 256, 0, stream>>>(y, w_proj, b_proj, out, B_ * T_, C_, C_);
}

// Round 2
// 988.788 us; speedup vs baseline: 4.4170x; 4.4170x over previous
//
#include <hip/hip_runtime.h>
#include <hip/hip_bf16.h>
#include <math.h>

#define B_ 8
#define T_ 1024
#define C_ 768
#define H_ 12
#define D_ 64

typedef __bf16 bf16x8 __attribute__((ext_vector_type(8)));
typedef float  f32x4  __attribute__((ext_vector_type(4)));
typedef unsigned short us8 __attribute__((ext_vector_type(8)));
typedef unsigned int   u32x4 __attribute__((ext_vector_type(4)));

__device__ __forceinline__ unsigned short f2bf(float f) {
    unsigned int u = __float_as_uint(f);
    u += 0x7fffu + ((u >> 16) & 1u);
    return (unsigned short)(u >> 16);
}

// ---------------- fp32 tiled GEMM + bias (unchanged from round 1) -----------
__global__ __launch_bounds__(256)
void gemm_bias(const float* __restrict__ A, const float* __restrict__ Bm,
               const float* __restrict__ bias, float* __restrict__ Cm,
               int M, int N, int K) {
    __shared__ float As[16][65];
    __shared__ float Bs[16][65];
    const int tid = threadIdx.x;
    const int tx = tid & 15;
    const int ty = tid >> 4;
    const int bm = blockIdx.y * 64;
    const int bn = blockIdx.x * 64;

    float acc[4][4];
#pragma unroll
    for (int i = 0; i < 4; i++)
#pragma unroll
        for (int j = 0; j < 4; j++) acc[i][j] = 0.f;

    for (int k0 = 0; k0 < K; k0 += 16) {
#pragma unroll
        for (int i = tid; i < 64 * 16; i += 256) {
            int mm = i >> 4;
            int kk = i & 15;
            As[kk][mm] = A[(size_t)(bm + mm) * K + k0 + kk];
        }
#pragma unroll
        for (int i = tid; i < 16 * 64; i += 256) {
            int kk = i >> 6;
            int nn = i & 63;
            Bs[kk][nn] = Bm[(size_t)(k0 + kk) * N + bn + nn];
        }
        __syncthreads();
#pragma unroll
        for (int kk = 0; kk < 16; kk++) {
            float a[4], bv[4];
#pragma unroll
            for (int i = 0; i < 4; i++) a[i] = As[kk][ty * 4 + i];
#pragma unroll
            for (int j = 0; j < 4; j++) bv[j] = Bs[kk][tx * 4 + j];
#pragma unroll
            for (int i = 0; i < 4; i++)
#pragma unroll
                for (int j = 0; j < 4; j++) acc[i][j] += a[i] * bv[j];
        }
        __syncthreads();
    }
#pragma unroll
    for (int i = 0; i < 4; i++) {
        int row = bm + ty * 4 + i;
#pragma unroll
        for (int j = 0; j < 4; j++) {
            int col = bn + tx * 4 + j;
            Cm[(size_t)row * N + col] = acc[i][j] + bias[col];
        }
    }
}

// ---------------- flash attention, bf16 MFMA ---------------------------------
// Block: 256 threads = 4 waves. Block tile: 64 queries x full K sweep.
// Wave w handles query rows [w*16, w*16+16) of the block's 64-row Q tile.
// LDS strides: Q/K/P rows padded to 72 bf16 (144 B = 9*16 B, odd multiple of
// 16 B -> conflict-free b128 frag reads). Vp rows = 66 dwords (2-lane/bank).
__global__ __launch_bounds__(256, 4)
void attn_mfma(const float* __restrict__ qkv, float* __restrict__ y) {
    __shared__ __align__(16) unsigned short Qs[64 * 72];
    __shared__ __align__(16) unsigned short Ks[64 * 72];
    __shared__ __align__(16) unsigned int   Vp[32 * 66];   // packed (k even | k odd<<16) per d
    __shared__ __align__(16) unsigned short Ps[4 * 16 * 72];

    const int tid  = threadIdx.x;
    const int wave = tid >> 6;
    const int lane = tid & 63;
    const int c    = lane & 15;   // MFMA "lane&15" dim
    const int quad = lane >> 4;

    const int qt = blockIdx.x;    // 0..15  (query tile)
    const int bh = blockIdx.y;    // 0..95
    const int b  = bh / H_;
    const int h  = bh - b * H_;
    const int q0 = qt * 64;

    const int RS = 3 * C_;  // 2304 floats per token row
    const float* qbase = qkv + ((size_t)(b * T_ + q0)) * RS + h * D_;
    const float* kbase = qkv + (size_t)b * T_ * RS + C_ + h * D_;
    const float* vbase = qkv + (size_t)b * T_ * RS + 2 * C_ + h * D_;

    // ---- stage Q once (pre-scaled by 1/sqrt(D)=0.125) ----
    for (int i = tid; i < 1024; i += 256) {
        int r = i >> 4, ch = i & 15;
        float4 v = *(const float4*)(qbase + (size_t)r * RS + ch * 4);
        ushort4 o;
        o.x = f2bf(v.x * 0.125f); o.y = f2bf(v.y * 0.125f);
        o.z = f2bf(v.z * 0.125f); o.w = f2bf(v.w * 0.125f);
        *(ushort4*)&Qs[r * 72 + ch * 4] = o;
    }

    f32x4 Oa[4];                 // O accumulator, C/D layout, 4 d-chunks
    float m_i[4], l_i[4];
#pragma unroll
    for (int d = 0; d < 4; d++) Oa[d] = (f32x4){0.f, 0.f, 0.f, 0.f};
#pragma unroll
    for (int r = 0; r < 4; r++) { m_i[r] = -INFINITY; l_i[r] = 0.f; }

    for (int kt = 0; kt <= qt; kt++) {
        __syncthreads();   // previous tile's LDS reads done
        // ---- stage K tile (64 x 64, bf16) ----
        for (int i = tid; i < 1024; i += 256) {
            int r = i >> 4, ch = i & 15;
            float4 v = *(const float4*)(kbase + (size_t)(kt * 64 + r) * RS + ch * 4);
            ushort4 o;
            o.x = f2bf(v.x); o.y = f2bf(v.y); o.z = f2bf(v.z); o.w = f2bf(v.w);
            *(ushort4*)&Ks[r * 72 + ch * 4] = o;
        }
        // ---- stage V as k-pair-packed dwords: Vp[k>>1][d] = (bf(k+1,d)<<16)|bf(k,d)
        for (int i = tid; i < 512; i += 256) {
            int rp = i >> 4, ch = i & 15;
            const float* p0 = vbase + (size_t)(kt * 64 + 2 * rp) * RS + ch * 4;
            float4 a  = *(const float4*)p0;
            float4 bb = *(const float4*)(p0 + RS);
            unsigned int* dst = &Vp[rp * 66 + ch * 4];
            dst[0] = ((unsigned)f2bf(bb.x) << 16) | f2bf(a.x);
            dst[1] = ((unsigned)f2bf(bb.y) << 16) | f2bf(a.y);
            dst[2] = ((unsigned)f2bf(bb.z) << 16) | f2bf(a.z);
            dst[3] = ((unsigned)f2bf(bb.w) << 16) | f2bf(a.w);
        }
        __syncthreads();

        // ---- S = Q K^T for this wave's 16 rows x 64 cols ----
        const int nmax = (kt == qt) ? wave : 3;  // cols fully above diagonal: skip
        f32x4 s[4];
#pragma unroll
        for (int n = 0; n < 4; n++) {
            if (n <= nmax) {
                s[n] = (f32x4){0.f, 0.f, 0.f, 0.f};
#pragma unroll
                for (int ks = 0; ks < 2; ks++) {
                    bf16x8 aq = __builtin_bit_cast(bf16x8,
                        *(const us8*)&Qs[(wave * 16 + c) * 72 + quad * 8 + ks * 32]);
                    bf16x8 bk = __builtin_bit_cast(bf16x8,
                        *(const us8*)&Ks[(n * 16 + c) * 72 + quad * 8 + ks * 32]);
                    s[n] = __builtin_amdgcn_mfma_f32_16x16x32_bf16(aq, bk, s[n], 0, 0, 0);
                }
                if (kt == qt && n == wave) {
                    // diagonal 16x16 sub-tile: mask cols > row
#pragma unroll
                    for (int r = 0; r < 4; r++)
                        if (c > quad * 4 + r) s[n][r] = -INFINITY;
                }
            } else {
                s[n] = (f32x4){-INFINITY, -INFINITY, -INFINITY, -INFINITY};
            }
        }

        // ---- online softmax (rows live across 16 lanes of each quad group) ----
        float al[4], rs[4];
#pragma unroll
        for (int r = 0; r < 4; r++) {
            float v = fmaxf(fmaxf(s[0][r], s[1][r]), fmaxf(s[2][r], s[3][r]));
            v = fmaxf(v, __shfl_xor(v, 1, 64));
            v = fmaxf(v, __shfl_xor(v, 2, 64));
            v = fmaxf(v, __shfl_xor(v, 4, 64));
            v = fmaxf(v, __shfl_xor(v, 8, 64));
            float mn = fmaxf(m_i[r], v);
            al[r] = __expf(m_i[r] - mn);
            m_i[r] = mn;
            rs[r] = 0.f;
        }
        unsigned short pb[4][4];
#pragma unroll
        for (int n = 0; n < 4; n++)
#pragma unroll
            for (int r = 0; r < 4; r++) {
                float p = __expf(s[n][r] - m_i[r]);   // -inf -> 0
                rs[r] += p;
                pb[n][r] = f2bf(p);
            }
        // write P (wave-private region; same-wave LDS ordering, no barrier)
        unsigned short* pw = &Ps[wave * 1152];
#pragma unroll
        for (int n = 0; n < 4; n++)
#pragma unroll
            for (int r = 0; r < 4; r++)
                pw[(quad * 4 + r) * 72 + n * 16 + c] = pb[n][r];

#pragma unroll
        for (int r = 0; r < 4; r++) {
            float v = rs[r];
            v += __shfl_xor(v, 1, 64);
            v += __shfl_xor(v, 2, 64);
            v += __shfl_xor(v, 4, 64);
            v += __shfl_xor(v, 8, 64);
            l_i[r] = l_i[r] * al[r] + v;
        }
#pragma unroll
        for (int d = 0; d < 4; d++)
#pragma unroll
            for (int r = 0; r < 4; r++) Oa[d][r] *= al[r];

        // ---- O += P V ----
        const unsigned short* pr = &Ps[wave * 1152 + c * 72];
#pragma unroll
        for (int d = 0; d < 4; d++) {
#pragma unroll
            for (int ks = 0; ks < 2; ks++) {
                bf16x8 ap = __builtin_bit_cast(bf16x8,
                    *(const us8*)&pr[quad * 8 + ks * 32]);
                u32x4 bv;
#pragma unroll
                for (int j2 = 0; j2 < 4; j2++)
                    bv[j2] = Vp[(ks * 16 + quad * 4 + j2) * 66 + d * 16 + c];
                bf16x8 vb = __builtin_bit_cast(bf16x8, bv);
                Oa[d] = __builtin_amdgcn_mfma_f32_16x16x32_bf16(ap, vb, Oa[d], 0, 0, 0);
            }
        }
    }

    // ---- epilogue: O / l -> y ----
    float* yrow = y + ((size_t)(b * T_ + q0 + wave * 16)) * C_ + h * D_;
#pragma unroll
    for (int r = 0; r < 4; r++) {
        float inv = 1.f / l_i[r];
#pragma unroll
        for (int d = 0; d < 4; d++)
            yrow[(size_t)(quad * 4 + r) * C_ + d * 16 + c] = Oa[d][r] * inv;
    }
}

extern "C" void kernel_launch(void* const* d_in, const int* in_sizes, int n_in,
                              void* d_out, int out_size, void* d_ws, size_t ws_size,
                              hipStream_t stream) {
    const float* x      = (const float*)d_in[0];
    const float* w_qkv  = (const float*)d_in[1];
    const float* b_qkv  = (const float*)d_in[2];
    const float* w_proj = (const float*)d_in[3];
    const float* b_proj = (const float*)d_in[4];
    float* out = (float*)d_out;

    float* qkv = (float*)d_ws;                       // [B*T, 3C]
    float* y   = qkv + (size_t)B_ * T_ * 3 * C_;     // [B*T, C]

    // 1) qkv = x @ w_qkv + b_qkv       M=8192 N=2304 K=768
    dim3 g1(3 * C_ / 64, B_ * T_ / 64);
    gemm_bias<<<g1, 256, 0, stream>>>(x, w_qkv, b_qkv, qkv, B_ * T_, 3 * C_, C_);

    // 2) flash attention -> y [B*T, C]
    dim3 g2(16, B_ * H_);   // x = q-tile (balance causal work across CUs)
    attn_mfma<<<g2, 256, 0, stream>>>(qkv, y);

    // 3) out = y @ w_proj + b_proj     M=8192 N=768 K=768
    dim3 g3(C_ / 64, B_ * T_ / 64);
    gemm_bias<<<g3, 256, 0, stream>>>(y, w_proj, b_proj, out, B_ * T_, C_, C_);
}

// Round 3
// 277.626 us; speedup vs baseline: 15.7316x; 3.5616x over previous
//
#include <hip/hip_runtime.h>
#include <math.h>

#define B_ 8
#define T_ 1024
#define C_ 768
#define H_ 12
#define D_ 64

typedef __bf16 bf16x8 __attribute__((ext_vector_type(8)));
typedef float  f32x4  __attribute__((ext_vector_type(4)));
typedef unsigned short us8 __attribute__((ext_vector_type(8)));

typedef __attribute__((address_space(3))) void lds_void;
typedef __attribute__((address_space(1))) const void glb_void;

__device__ __forceinline__ unsigned short f2bf(float f) {
    unsigned int u = __float_as_uint(f);
    u += 0x7fffu + ((u >> 16) & 1u);
    return (unsigned short)(u >> 16);
}
__device__ __forceinline__ float bf2f(unsigned short h) {
    return __uint_as_float(((unsigned)h) << 16);
}

// ---------------- prep: fp32 -> bf16 elementwise (x) ------------------------
__global__ __launch_bounds__(256)
void convert_bf16(const float* __restrict__ in, unsigned short* __restrict__ out, int n4) {
    int idx = blockIdx.x * 256 + threadIdx.x;
    if (idx < n4) {
        float4 v = ((const float4*)in)[idx];
        ushort4 o;
        o.x = f2bf(v.x); o.y = f2bf(v.y); o.z = f2bf(v.z); o.w = f2bf(v.w);
        ((ushort4*)out)[idx] = o;
    }
}

// ---------------- prep: W[K][N] fp32 -> Wt[N][K] bf16 (tiled transpose) -----
__global__ __launch_bounds__(256)
void transpose_w(const float* __restrict__ W, unsigned short* __restrict__ Wt,
                 int K, int N) {
    __shared__ unsigned short Ts[64][65];
    const int n0 = blockIdx.x * 64, k0 = blockIdx.y * 64;
    for (int i = threadIdx.x; i < 4096; i += 256) {
        int n = i & 63, k = i >> 6;
        Ts[n][k] = f2bf(W[(size_t)(k0 + k) * N + n0 + n]);
    }
    __syncthreads();
    for (int i = threadIdx.x; i < 4096; i += 256) {
        int k = i & 63, n = i >> 6;
        Wt[(size_t)(n0 + n) * K + k0 + k] = Ts[n][k];
    }
}

// ---------------- bf16 MFMA GEMM:  C[M,N] = A[M,K] · Bt[N,K]^T + bias -------
// 128x128 tile, BK=32, 4 waves in 2x2, each wave 4x4 16x16x32 MFMA frags.
// LDS tiles are 512 x 16-byte "cells"; logical cell L = row*4 + kchunk is
// stored at L' = L ^ ((L>>3)&7). Staging (global_load_lds, lane*16 dest) stays
// coalesced; fragment ds_read_b128 tiles all 32 banks conflict-free.
template<int OUT_BF16>
__global__ __launch_bounds__(256)
void gemm_bf16_bt(const unsigned short* __restrict__ A,
                  const unsigned short* __restrict__ Bt,
                  const float* __restrict__ bias,
                  void* __restrict__ Cout,
                  int M, int N, int K) {
    __shared__ __align__(16) unsigned short As[4096];
    __shared__ __align__(16) unsigned short Bs[4096];

    const int tid  = threadIdx.x;
    const int lane = tid & 63;
    const int c    = lane & 15;
    const int quad = lane >> 4;
    const int wave = tid >> 6;
    const int wm   = (wave >> 1) * 64;
    const int wn   = (wave & 1) * 64;
    const int bm   = blockIdx.y * 128;
    const int bn   = blockIdx.x * 128;

    // staging: this thread's swizzled cell for pass 0/1 -> (row, kchunk)
    const int Lp0 = tid;
    const int Lp1 = 256 + tid;
    const int L0  = Lp0 ^ ((Lp0 >> 3) & 7);
    const int L1  = Lp1 ^ ((Lp1 >> 3) & 7);
    const unsigned short* aSrc0 = A  + (size_t)(bm + (L0 >> 2)) * K + (L0 & 3) * 8;
    const unsigned short* aSrc1 = A  + (size_t)(bm + (L1 >> 2)) * K + (L1 & 3) * 8;
    const unsigned short* bSrc0 = Bt + (size_t)(bn + (L0 >> 2)) * K + (L0 & 3) * 8;
    const unsigned short* bSrc1 = Bt + (size_t)(bn + (L1 >> 2)) * K + (L1 & 3) * 8;
    unsigned short* ldsA0 = As + (tid & 0xC0) * 8;          // wave-uniform bases
    unsigned short* ldsA1 = As + (256 + (tid & 0xC0)) * 8;
    unsigned short* ldsB0 = Bs + (tid & 0xC0) * 8;
    unsigned short* ldsB1 = Bs + (256 + (tid & 0xC0)) * 8;

    // fragment LDS offsets (ushort units), swizzle folds into a constant
    const int xorv = (c >> 1) & 7;
    int aoff[4], boff[4];
#pragma unroll
    for (int i = 0; i < 4; i++) {
        aoff[i] = ((((wm + i * 16 + c) << 2) + quad) ^ xorv) * 8;
        boff[i] = ((((wn + i * 16 + c) << 2) + quad) ^ xorv) * 8;
    }

    f32x4 acc[4][4];
#pragma unroll
    for (int i = 0; i < 4; i++)
#pragma unroll
        for (int j = 0; j < 4; j++) acc[i][j] = (f32x4){0.f, 0.f, 0.f, 0.f};

    for (int kt = 0; kt < K; kt += 32) {
        __syncthreads();   // previous iteration's frag reads done
        __builtin_amdgcn_global_load_lds((glb_void*)aSrc0, (lds_void*)ldsA0, 16, 0, 0);
        __builtin_amdgcn_global_load_lds((glb_void*)aSrc1, (lds_void*)ldsA1, 16, 0, 0);
        __builtin_amdgcn_global_load_lds((glb_void*)bSrc0, (lds_void*)ldsB0, 16, 0, 0);
        __builtin_amdgcn_global_load_lds((glb_void*)bSrc1, (lds_void*)ldsB1, 16, 0, 0);
        aSrc0 += 32; aSrc1 += 32; bSrc0 += 32; bSrc1 += 32;
        __syncthreads();   // staging complete (barrier drains vmcnt)

        bf16x8 af[4], bfr[4];
#pragma unroll
        for (int i = 0; i < 4; i++)
            af[i] = __builtin_bit_cast(bf16x8, *(const us8*)&As[aoff[i]]);
#pragma unroll
        for (int j = 0; j < 4; j++)
            bfr[j] = __builtin_bit_cast(bf16x8, *(const us8*)&Bs[boff[j]]);
#pragma unroll
        for (int i = 0; i < 4; i++)
#pragma unroll
            for (int j = 0; j < 4; j++)
                acc[i][j] = __builtin_amdgcn_mfma_f32_16x16x32_bf16(af[i], bfr[j], acc[i][j], 0, 0, 0);
    }

    float bs[4];
#pragma unroll
    for (int j = 0; j < 4; j++) bs[j] = bias[bn + wn + j * 16 + c];
#pragma unroll
    for (int i = 0; i < 4; i++) {
        const int gm = bm + wm + i * 16 + quad * 4;
#pragma unroll
        for (int r = 0; r < 4; r++) {
            const size_t ro = (size_t)(gm + r) * N;
#pragma unroll
            for (int j = 0; j < 4; j++) {
                const float v = acc[i][j][r] + bs[j];
                const int gn = bn + wn + j * 16 + c;
                if (OUT_BF16) ((unsigned short*)Cout)[ro + gn] = f2bf(v);
                else          ((float*)Cout)[ro + gn] = v;
            }
        }
    }
}

// ---------------- flash attention, bf16 in / bf16 out -----------------------
__global__ __launch_bounds__(256, 4)
void attn_mfma(const unsigned short* __restrict__ qkv, unsigned short* __restrict__ y) {
    __shared__ __align__(16) unsigned short Qs[64 * 72];
    __shared__ __align__(16) unsigned short Ks[64 * 72];
    __shared__ __align__(16) unsigned int   Vp[32 * 66];
    __shared__ __align__(16) unsigned short Ps[4 * 16 * 72];

    const int tid  = threadIdx.x;
    const int wave = tid >> 6;
    const int lane = tid & 63;
    const int c    = lane & 15;
    const int quad = lane >> 4;

    const int qt = blockIdx.x;
    const int bh = blockIdx.y;
    const int b  = bh / H_;
    const int h  = bh - b * H_;
    const int q0 = qt * 64;

    const int RS = 3 * C_;
    const unsigned short* qbase = qkv + ((size_t)(b * T_ + q0)) * RS + h * D_;
    const unsigned short* kbase = qkv + (size_t)b * T_ * RS + C_ + h * D_;
    const unsigned short* vbase = qkv + (size_t)b * T_ * RS + 2 * C_ + h * D_;

    // ---- stage Q once, scaled by 0.125 (exact in bf16) ----
    for (int i = tid; i < 512; i += 256) {
        int r = i >> 3, ch = i & 7;
        us8 v = *(const us8*)(qbase + (size_t)r * RS + ch * 8);
        us8 o;
#pragma unroll
        for (int t = 0; t < 8; t++) o[t] = f2bf(bf2f(v[t]) * 0.125f);
        *(us8*)&Qs[r * 72 + ch * 8] = o;
    }

    f32x4 Oa[4];
    float m_i[4], l_i[4];
#pragma unroll
    for (int d = 0; d < 4; d++) Oa[d] = (f32x4){0.f, 0.f, 0.f, 0.f};
#pragma unroll
    for (int r = 0; r < 4; r++) { m_i[r] = -INFINITY; l_i[r] = 0.f; }

    for (int kt = 0; kt <= qt; kt++) {
        __syncthreads();
        // K tile: straight bf16 copy
        for (int i = tid; i < 512; i += 256) {
            int r = i >> 3, ch = i & 7;
            *(us8*)&Ks[r * 72 + ch * 8] =
                *(const us8*)(kbase + (size_t)(kt * 64 + r) * RS + ch * 8);
        }
        // V tile: pack k-pairs into dwords
        for (int i = tid; i < 512; i += 256) {
            int rp = i >> 4, ch = i & 15;
            const unsigned short* p0 = vbase + (size_t)(kt * 64 + 2 * rp) * RS + ch * 4;
            ushort4 a  = *(const ushort4*)p0;
            ushort4 bb = *(const ushort4*)(p0 + RS);
            unsigned int* dst = &Vp[rp * 66 + ch * 4];
            dst[0] = a.x | ((unsigned)bb.x << 16);
            dst[1] = a.y | ((unsigned)bb.y << 16);
            dst[2] = a.z | ((unsigned)bb.z << 16);
            dst[3] = a.w | ((unsigned)bb.w << 16);
        }
        __syncthreads();

        const int nmax = (kt == qt) ? wave : 3;
        f32x4 s[4];
#pragma unroll
        for (int n = 0; n < 4; n++) {
            if (n <= nmax) {
                s[n] = (f32x4){0.f, 0.f, 0.f, 0.f};
#pragma unroll
                for (int ks = 0; ks < 2; ks++) {
                    bf16x8 aq = __builtin_bit_cast(bf16x8,
                        *(const us8*)&Qs[(wave * 16 + c) * 72 + quad * 8 + ks * 32]);
                    bf16x8 bk = __builtin_bit_cast(bf16x8,
                        *(const us8*)&Ks[(n * 16 + c) * 72 + quad * 8 + ks * 32]);
                    s[n] = __builtin_amdgcn_mfma_f32_16x16x32_bf16(aq, bk, s[n], 0, 0, 0);
                }
                if (kt == qt && n == wave) {
#pragma unroll
                    for (int r = 0; r < 4; r++)
                        if (c > quad * 4 + r) s[n][r] = -INFINITY;
                }
            } else {
                s[n] = (f32x4){-INFINITY, -INFINITY, -INFINITY, -INFINITY};
            }
        }

        float al[4], rs[4];
#pragma unroll
        for (int r = 0; r < 4; r++) {
            float v = fmaxf(fmaxf(s[0][r], s[1][r]), fmaxf(s[2][r], s[3][r]));
            v = fmaxf(v, __shfl_xor(v, 1, 64));
            v = fmaxf(v, __shfl_xor(v, 2, 64));
            v = fmaxf(v, __shfl_xor(v, 4, 64));
            v = fmaxf(v, __shfl_xor(v, 8, 64));
            float mn = fmaxf(m_i[r], v);
            al[r] = __expf(m_i[r] - mn);
            m_i[r] = mn;
            rs[r] = 0.f;
        }
        unsigned short pb[4][4];
#pragma unroll
        for (int n = 0; n < 4; n++)
#pragma unroll
            for (int r = 0; r < 4; r++) {
                float p = __expf(s[n][r] - m_i[r]);
                rs[r] += p;
                pb[n][r] = f2bf(p);
            }
        unsigned short* pw = &Ps[wave * 1152];
#pragma unroll
        for (int n = 0; n < 4; n++)
#pragma unroll
            for (int r = 0; r < 4; r++)
                pw[(quad * 4 + r) * 72 + n * 16 + c] = pb[n][r];

#pragma unroll
        for (int r = 0; r < 4; r++) {
            float v = rs[r];
            v += __shfl_xor(v, 1, 64);
            v += __shfl_xor(v, 2, 64);
            v += __shfl_xor(v, 4, 64);
            v += __shfl_xor(v, 8, 64);
            l_i[r] = l_i[r] * al[r] + v;
        }
#pragma unroll
        for (int d = 0; d < 4; d++)
#pragma unroll
            for (int r = 0; r < 4; r++) Oa[d][r] *= al[r];

        const unsigned short* pr = &Ps[wave * 1152 + c * 72];
#pragma unroll
        for (int d = 0; d < 4; d++) {
#pragma unroll
            for (int ks = 0; ks < 2; ks++) {
                bf16x8 ap = __builtin_bit_cast(bf16x8,
                    *(const us8*)&pr[quad * 8 + ks * 32]);
                unsigned int bv[4];
#pragma unroll
                for (int j2 = 0; j2 < 4; j2++)
                    bv[j2] = Vp[(ks * 16 + quad * 4 + j2) * 66 + d * 16 + c];
                bf16x8 vb = __builtin_bit_cast(bf16x8, *(us8*)bv);
                Oa[d] = __builtin_amdgcn_mfma_f32_16x16x32_bf16(ap, vb, Oa[d], 0, 0, 0);
            }
        }
    }

    unsigned short* yrow = y + ((size_t)(b * T_ + q0 + wave * 16)) * C_ + h * D_;
#pragma unroll
    for (int r = 0; r < 4; r++) {
        float inv = 1.f / l_i[r];
#pragma unroll
        for (int d = 0; d < 4; d++)
            yrow[(size_t)(quad * 4 + r) * C_ + d * 16 + c] = f2bf(Oa[d][r] * inv);
    }
}

extern "C" void kernel_launch(void* const* d_in, const int* in_sizes, int n_in,
                              void* d_out, int out_size, void* d_ws, size_t ws_size,
                              hipStream_t stream) {
    const float* x      = (const float*)d_in[0];
    const float* w_qkv  = (const float*)d_in[1];
    const float* b_qkv  = (const float*)d_in[2];
    const float* w_proj = (const float*)d_in[3];
    const float* b_proj = (const float*)d_in[4];
    float* out = (float*)d_out;

    unsigned short* xb   = (unsigned short*)d_ws;                 // [8192][768]
    unsigned short* wqT  = xb   + (size_t)B_ * T_ * C_;           // [2304][768]
    unsigned short* wpT  = wqT  + (size_t)3 * C_ * C_;            // [768][768]
    unsigned short* qkvb = wpT  + (size_t)C_ * C_;                // [8192][2304]
    unsigned short* yb   = qkvb + (size_t)B_ * T_ * 3 * C_;       // [8192][768]

    const int nx4 = B_ * T_ * C_ / 4;
    convert_bf16<<<(nx4 + 255) / 256, 256, 0, stream>>>(x, xb, nx4);
    transpose_w<<<dim3(3 * C_ / 64, C_ / 64), 256, 0, stream>>>(w_qkv, wqT, C_, 3 * C_);
    transpose_w<<<dim3(C_ / 64, C_ / 64), 256, 0, stream>>>(w_proj, wpT, C_, C_);

    // qkv = x @ w_qkv + b_qkv   (bf16 out)
    gemm_bf16_bt<1><<<dim3(3 * C_ / 128, B_ * T_ / 128), 256, 0, stream>>>(
        xb, wqT, b_qkv, qkvb, B_ * T_, 3 * C_, C_);

    // flash attention -> y (bf16)
    attn_mfma<<<dim3(16, B_ * H_), 256, 0, stream>>>(qkvb, yb);

    // out = y @ w_proj + b_proj (fp32 out)
    gemm_bf16_bt<0><<<dim3(C_ / 128, B_ * T_ / 128), 256, 0, stream>>>(
        yb, wpT, b_proj, out, B_ * T_, C_, C_);
}

// Round 4
// 244.684 us; speedup vs baseline: 17.8495x; 1.1346x over previous
//
#include <hip/hip_runtime.h>
#include <math.h>

#define B_ 8
#define T_ 1024
#define C_ 768
#define H_ 12
#define D_ 64

typedef __bf16 bf16x8 __attribute__((ext_vector_type(8)));
typedef float  f32x4  __attribute__((ext_vector_type(4)));
typedef unsigned short us8 __attribute__((ext_vector_type(8)));

typedef __attribute__((address_space(3))) void lds_void;
typedef __attribute__((address_space(1))) const void glb_void;

__device__ __forceinline__ unsigned short f2bf(float f) {
    unsigned int u = __float_as_uint(f);
    u += 0x7fffu + ((u >> 16) & 1u);
    return (unsigned short)(u >> 16);
}

// ---------------- prep: fp32 -> bf16 elementwise (x) ------------------------
__global__ __launch_bounds__(256)
void convert_bf16(const float* __restrict__ in, unsigned short* __restrict__ out, int n4) {
    int idx = blockIdx.x * 256 + threadIdx.x;
    if (idx < n4) {
        float4 v = ((const float4*)in)[idx];
        ushort4 o;
        o.x = f2bf(v.x); o.y = f2bf(v.y); o.z = f2bf(v.z); o.w = f2bf(v.w);
        ((ushort4*)out)[idx] = o;
    }
}

// ---------------- prep: W[K][N] fp32 -> Wt[N][K] bf16 (tiled transpose) -----
__global__ __launch_bounds__(256)
void transpose_w(const float* __restrict__ W, unsigned short* __restrict__ Wt,
                 int K, int N) {
    __shared__ unsigned short Ts[64][65];
    const int n0 = blockIdx.x * 64, k0 = blockIdx.y * 64;
    for (int i = threadIdx.x; i < 4096; i += 256) {
        int n = i & 63, k = i >> 6;
        Ts[n][k] = f2bf(W[(size_t)(k0 + k) * N + n0 + n]);
    }
    __syncthreads();
    for (int i = threadIdx.x; i < 4096; i += 256) {
        int k = i & 63, n = i >> 6;
        Wt[(size_t)(n0 + n) * K + k0 + k] = Ts[n][k];
    }
}

// ---------------- bf16 MFMA GEMM:  C[M,N] = A[M,K] · Bt[N,K]^T + bias -------
template<int OUT_BF16>
__global__ __launch_bounds__(256)
void gemm_bf16_bt(const unsigned short* __restrict__ A,
                  const unsigned short* __restrict__ Bt,
                  const float* __restrict__ bias,
                  void* __restrict__ Cout,
                  int M, int N, int K) {
    __shared__ __align__(16) unsigned short As[4096];
    __shared__ __align__(16) unsigned short Bs[4096];

    const int tid  = threadIdx.x;
    const int lane = tid & 63;
    const int c    = lane & 15;
    const int quad = lane >> 4;
    const int wave = tid >> 6;
    const int wm   = (wave >> 1) * 64;
    const int wn   = (wave & 1) * 64;
    const int bm   = blockIdx.y * 128;
    const int bn   = blockIdx.x * 128;

    const int Lp0 = tid;
    const int Lp1 = 256 + tid;
    const int L0  = Lp0 ^ ((Lp0 >> 3) & 7);
    const int L1  = Lp1 ^ ((Lp1 >> 3) & 7);
    const unsigned short* aSrc0 = A  + (size_t)(bm + (L0 >> 2)) * K + (L0 & 3) * 8;
    const unsigned short* aSrc1 = A  + (size_t)(bm + (L1 >> 2)) * K + (L1 & 3) * 8;
    const unsigned short* bSrc0 = Bt + (size_t)(bn + (L0 >> 2)) * K + (L0 & 3) * 8;
    const unsigned short* bSrc1 = Bt + (size_t)(bn + (L1 >> 2)) * K + (L1 & 3) * 8;
    unsigned short* ldsA0 = As + (tid & 0xC0) * 8;
    unsigned short* ldsA1 = As + (256 + (tid & 0xC0)) * 8;
    unsigned short* ldsB0 = Bs + (tid & 0xC0) * 8;
    unsigned short* ldsB1 = Bs + (256 + (tid & 0xC0)) * 8;

    const int xorv = (c >> 1) & 7;
    int aoff[4], boff[4];
#pragma unroll
    for (int i = 0; i < 4; i++) {
        aoff[i] = ((((wm + i * 16 + c) << 2) + quad) ^ xorv) * 8;
        boff[i] = ((((wn + i * 16 + c) << 2) + quad) ^ xorv) * 8;
    }

    f32x4 acc[4][4];
#pragma unroll
    for (int i = 0; i < 4; i++)
#pragma unroll
        for (int j = 0; j < 4; j++) acc[i][j] = (f32x4){0.f, 0.f, 0.f, 0.f};

    for (int kt = 0; kt < K; kt += 32) {
        __syncthreads();
        __builtin_amdgcn_global_load_lds((glb_void*)aSrc0, (lds_void*)ldsA0, 16, 0, 0);
        __builtin_amdgcn_global_load_lds((glb_void*)aSrc1, (lds_void*)ldsA1, 16, 0, 0);
        __builtin_amdgcn_global_load_lds((glb_void*)bSrc0, (lds_void*)ldsB0, 16, 0, 0);
        __builtin_amdgcn_global_load_lds((glb_void*)bSrc1, (lds_void*)ldsB1, 16, 0, 0);
        aSrc0 += 32; aSrc1 += 32; bSrc0 += 32; bSrc1 += 32;
        __syncthreads();

        bf16x8 af[4], bfr[4];
#pragma unroll
        for (int i = 0; i < 4; i++)
            af[i] = __builtin_bit_cast(bf16x8, *(const us8*)&As[aoff[i]]);
#pragma unroll
        for (int j = 0; j < 4; j++)
            bfr[j] = __builtin_bit_cast(bf16x8, *(const us8*)&Bs[boff[j]]);
#pragma unroll
        for (int i = 0; i < 4; i++)
#pragma unroll
            for (int j = 0; j < 4; j++)
                acc[i][j] = __builtin_amdgcn_mfma_f32_16x16x32_bf16(af[i], bfr[j], acc[i][j], 0, 0, 0);
    }

    float bs[4];
#pragma unroll
    for (int j = 0; j < 4; j++) bs[j] = bias[bn + wn + j * 16 + c];
#pragma unroll
    for (int i = 0; i < 4; i++) {
        const int gm = bm + wm + i * 16 + quad * 4;
#pragma unroll
        for (int r = 0; r < 4; r++) {
            const size_t ro = (size_t)(gm + r) * N;
#pragma unroll
            for (int j = 0; j < 4; j++) {
                const float v = acc[i][j][r] + bs[j];
                const int gn = bn + wn + j * 16 + c;
                if (OUT_BF16) ((unsigned short*)Cout)[ro + gn] = f2bf(v);
                else          ((float*)Cout)[ro + gn] = v;
            }
        }
    }
}

// ---------------- flash attention: Q in regs, K/V register-prefetch ---------
// 1-D grid, XCD-swizzled: id = (bh%8) + 8*qt + 128*(bh/8) so a head's 16
// q-tile blocks share id%8 -> same XCD -> its K/V (256KB) stays L2-resident.
__global__ __launch_bounds__(256, 4)
void attn_mfma(const unsigned short* __restrict__ qkv, unsigned short* __restrict__ y) {
    __shared__ __align__(16) unsigned short Ks[64 * 72];
    __shared__ __align__(16) unsigned int   Vp[32 * 66];
    __shared__ __align__(16) unsigned short Ps[4 * 16 * 72];

    const int tid  = threadIdx.x;
    const int wave = tid >> 6;
    const int lane = tid & 63;
    const int c    = lane & 15;
    const int quad = lane >> 4;

    const int id = blockIdx.x;
    const int qt = (id >> 3) & 15;
    const int bh = (id >> 7) * 8 + (id & 7);
    const int b  = bh / H_;
    const int h  = bh - b * H_;
    const int q0 = qt * 64;

    const int RS = 3 * C_;
    const unsigned short* kbase = qkv + (size_t)b * T_ * RS + C_ + h * D_;
    const unsigned short* vbase = qkv + (size_t)b * T_ * RS + 2 * C_ + h * D_;

    // ---- Q fragments directly to registers (A-layout: row=c, k=quad*8+j) ----
    const unsigned short* qrow =
        qkv + ((size_t)(b * T_ + q0 + wave * 16 + c)) * RS + h * D_ + quad * 8;
    bf16x8 qf[2];
    qf[0] = __builtin_bit_cast(bf16x8, *(const us8*)qrow);
    qf[1] = __builtin_bit_cast(bf16x8, *(const us8*)(qrow + 32));

    // per-thread staging coords
    const int kr0 = tid >> 3, kc0 = tid & 7;
    const int vr0 = tid >> 4, vc0 = tid & 15;

    us8 kA, kB;
    ushort4 vA0, vB0, vA1, vB1;

    // prefetch kt=0
    {
        const unsigned short* kp = kbase;
        kA = *(const us8*)(kp + (size_t)kr0 * RS + kc0 * 8);
        kB = *(const us8*)(kp + (size_t)(kr0 + 32) * RS + kc0 * 8);
        const unsigned short* p0 = vbase + (size_t)(2 * vr0) * RS + vc0 * 4;
        vA0 = *(const ushort4*)p0;  vB0 = *(const ushort4*)(p0 + RS);
        const unsigned short* p1 = vbase + (size_t)(2 * (vr0 + 16)) * RS + vc0 * 4;
        vA1 = *(const ushort4*)p1;  vB1 = *(const ushort4*)(p1 + RS);
    }

    f32x4 Oa[4];
    float m_i[4], l_i[4];
#pragma unroll
    for (int d = 0; d < 4; d++) Oa[d] = (f32x4){0.f, 0.f, 0.f, 0.f};
#pragma unroll
    for (int r = 0; r < 4; r++) { m_i[r] = -INFINITY; l_i[r] = 0.f; }

    for (int kt = 0; kt <= qt; kt++) {
        __syncthreads();   // prev iter's LDS reads done
        // regs -> LDS
        *(us8*)&Ks[kr0 * 72 + kc0 * 8] = kA;
        *(us8*)&Ks[(kr0 + 32) * 72 + kc0 * 8] = kB;
        {
            unsigned int* d0 = &Vp[vr0 * 66 + vc0 * 4];
            d0[0] = vA0.x | ((unsigned)vB0.x << 16);
            d0[1] = vA0.y | ((unsigned)vB0.y << 16);
            d0[2] = vA0.z | ((unsigned)vB0.z << 16);
            d0[3] = vA0.w | ((unsigned)vB0.w << 16);
            unsigned int* d1 = &Vp[(vr0 + 16) * 66 + vc0 * 4];
            d1[0] = vA1.x | ((unsigned)vB1.x << 16);
            d1[1] = vA1.y | ((unsigned)vB1.y << 16);
            d1[2] = vA1.z | ((unsigned)vB1.z << 16);
            d1[3] = vA1.w | ((unsigned)vB1.w << 16);
        }
        __syncthreads();   // staging visible

        // prefetch kt+1 while computing kt
        if (kt < qt) {
            const unsigned short* kp = kbase + (size_t)((kt + 1) * 64) * RS;
            kA = *(const us8*)(kp + (size_t)kr0 * RS + kc0 * 8);
            kB = *(const us8*)(kp + (size_t)(kr0 + 32) * RS + kc0 * 8);
            const unsigned short* vp = vbase + (size_t)((kt + 1) * 64) * RS;
            const unsigned short* p0 = vp + (size_t)(2 * vr0) * RS + vc0 * 4;
            vA0 = *(const ushort4*)p0;  vB0 = *(const ushort4*)(p0 + RS);
            const unsigned short* p1 = vp + (size_t)(2 * (vr0 + 16)) * RS + vc0 * 4;
            vA1 = *(const ushort4*)p1;  vB1 = *(const ushort4*)(p1 + RS);
        }

        // ---- S = Q K^T (this wave's 16 rows x 64 cols) ----
        const int dRow = q0 + wave * 16 - kt * 64;         // >= 0
        int nmax = (dRow + 15) >> 4; if (nmax > 3) nmax = 3;
        f32x4 s[4];
#pragma unroll
        for (int n = 0; n < 4; n++) {
            if (n <= nmax) {
                s[n] = (f32x4){0.f, 0.f, 0.f, 0.f};
#pragma unroll
                for (int ks = 0; ks < 2; ks++) {
                    bf16x8 bk = __builtin_bit_cast(bf16x8,
                        *(const us8*)&Ks[(n * 16 + c) * 72 + quad * 8 + ks * 32]);
                    s[n] = __builtin_amdgcn_mfma_f32_16x16x32_bf16(qf[ks], bk, s[n], 0, 0, 0);
                }
                s[n] *= 0.125f;
                if (n * 16 + 15 > dRow) {
#pragma unroll
                    for (int r = 0; r < 4; r++)
                        if (n * 16 + c > dRow + quad * 4 + r) s[n][r] = -INFINITY;
                }
            } else {
                s[n] = (f32x4){-INFINITY, -INFINITY, -INFINITY, -INFINITY};
            }
        }

        // ---- online softmax ----
        float al[4], rs[4];
#pragma unroll
        for (int r = 0; r < 4; r++) {
            float v = fmaxf(fmaxf(s[0][r], s[1][r]), fmaxf(s[2][r], s[3][r]));
            v = fmaxf(v, __shfl_xor(v, 1, 64));
            v = fmaxf(v, __shfl_xor(v, 2, 64));
            v = fmaxf(v, __shfl_xor(v, 4, 64));
            v = fmaxf(v, __shfl_xor(v, 8, 64));
            float mn = fmaxf(m_i[r], v);
            al[r] = __expf(m_i[r] - mn);
            m_i[r] = mn;
            rs[r] = 0.f;
        }
        unsigned short pb[4][4];
#pragma unroll
        for (int n = 0; n < 4; n++)
#pragma unroll
            for (int r = 0; r < 4; r++) {
                float p = __expf(s[n][r] - m_i[r]);
                rs[r] += p;
                pb[n][r] = f2bf(p);
            }
        unsigned short* pw = &Ps[wave * 1152];
#pragma unroll
        for (int n = 0; n < 4; n++)
#pragma unroll
            for (int r = 0; r < 4; r++)
                pw[(quad * 4 + r) * 72 + n * 16 + c] = pb[n][r];

#pragma unroll
        for (int r = 0; r < 4; r++) {
            float v = rs[r];
            v += __shfl_xor(v, 1, 64);
            v += __shfl_xor(v, 2, 64);
            v += __shfl_xor(v, 4, 64);
            v += __shfl_xor(v, 8, 64);
            l_i[r] = l_i[r] * al[r] + v;
        }
#pragma unroll
        for (int d = 0; d < 4; d++)
#pragma unroll
            for (int r = 0; r < 4; r++) Oa[d][r] *= al[r];

        // ---- O += P V ----
        const unsigned short* pr = &Ps[wave * 1152 + c * 72];
#pragma unroll
        for (int d = 0; d < 4; d++) {
#pragma unroll
            for (int ks = 0; ks < 2; ks++) {
                bf16x8 ap = __builtin_bit_cast(bf16x8,
                    *(const us8*)&pr[quad * 8 + ks * 32]);
                unsigned int bv[4];
#pragma unroll
                for (int j2 = 0; j2 < 4; j2++)
                    bv[j2] = Vp[(ks * 16 + quad * 4 + j2) * 66 + d * 16 + c];
                bf16x8 vb = __builtin_bit_cast(bf16x8, *(us8*)bv);
                Oa[d] = __builtin_amdgcn_mfma_f32_16x16x32_bf16(ap, vb, Oa[d], 0, 0, 0);
            }
        }
    }

    unsigned short* yrow = y + ((size_t)(b * T_ + q0 + wave * 16)) * C_ + h * D_;
#pragma unroll
    for (int r = 0; r < 4; r++) {
        float inv = 1.f / l_i[r];
#pragma unroll
        for (int d = 0; d < 4; d++)
            yrow[(size_t)(quad * 4 + r) * C_ + d * 16 + c] = f2bf(Oa[d][r] * inv);
    }
}

extern "C" void kernel_launch(void* const* d_in, const int* in_sizes, int n_in,
                              void* d_out, int out_size, void* d_ws, size_t ws_size,
                              hipStream_t stream) {
    const float* x      = (const float*)d_in[0];
    const float* w_qkv  = (const float*)d_in[1];
    const float* b_qkv  = (const float*)d_in[2];
    const float* w_proj = (const float*)d_in[3];
    const float* b_proj = (const float*)d_in[4];
    float* out = (float*)d_out;

    unsigned short* xb   = (unsigned short*)d_ws;                 // [8192][768]
    unsigned short* wqT  = xb   + (size_t)B_ * T_ * C_;           // [2304][768]
    unsigned short* wpT  = wqT  + (size_t)3 * C_ * C_;            // [768][768]
    unsigned short* qkvb = wpT  + (size_t)C_ * C_;                // [8192][2304]
    unsigned short* yb   = qkvb + (size_t)B_ * T_ * 3 * C_;       // [8192][768]

    const int nx4 = B_ * T_ * C_ / 4;
    convert_bf16<<<(nx4 + 255) / 256, 256, 0, stream>>>(x, xb, nx4);
    transpose_w<<<dim3(3 * C_ / 64, C_ / 64), 256, 0, stream>>>(w_qkv, wqT, C_, 3 * C_);
    transpose_w<<<dim3(C_ / 64, C_ / 64), 256, 0, stream>>>(w_proj, wpT, C_, C_);

    // qkv = x @ w_qkv + b_qkv   (bf16 out)
    gemm_bf16_bt<1><<<dim3(3 * C_ / 128, B_ * T_ / 128), 256, 0, stream>>>(
        xb, wqT, b_qkv, qkvb, B_ * T_, 3 * C_, C_);

    // flash attention -> y (bf16), XCD-swizzled 1-D grid
    attn_mfma<<<16 * B_ * H_, 256, 0, stream>>>(qkvb, yb);

    // out = y @ w_proj + b_proj (fp32 out)
    gemm_bf16_bt<0><<<dim3(C_ / 128, B_ * T_ / 128), 256, 0, stream>>>(
        yb, wpT, b_proj, out, B_ * T_, C_, C_);
}

// Round 5
// 229.230 us; speedup vs baseline: 19.0529x; 1.0674x over previous
//
#include <hip/hip_runtime.h>
#include <math.h>

#define B_ 8
#define T_ 1024
#define C_ 768
#define H_ 12
#define D_ 64

typedef __bf16 bf16x8 __attribute__((ext_vector_type(8)));
typedef float  f32x4  __attribute__((ext_vector_type(4)));
typedef unsigned short us8 __attribute__((ext_vector_type(8)));

typedef __attribute__((address_space(3))) void lds_void;
typedef __attribute__((address_space(1))) const void glb_void;

__device__ __forceinline__ unsigned short f2bf(float f) {
    unsigned int u = __float_as_uint(f);
    u += 0x7fffu + ((u >> 16) & 1u);
    return (unsigned short)(u >> 16);
}

// ---------------- prep: fp32 -> bf16 elementwise (x) ------------------------
__global__ __launch_bounds__(256)
void convert_bf16(const float* __restrict__ in, unsigned short* __restrict__ out, int n4) {
    int idx = blockIdx.x * 256 + threadIdx.x;
    if (idx < n4) {
        float4 v = ((const float4*)in)[idx];
        ushort4 o;
        o.x = f2bf(v.x); o.y = f2bf(v.y); o.z = f2bf(v.z); o.w = f2bf(v.w);
        ((ushort4*)out)[idx] = o;
    }
}

// ---------------- prep: W[K][N] fp32 -> Wt[N][K] bf16 (tiled transpose) -----
__global__ __launch_bounds__(256)
void transpose_w(const float* __restrict__ W, unsigned short* __restrict__ Wt,
                 int K, int N) {
    __shared__ unsigned short Ts[64][65];
    const int n0 = blockIdx.x * 64, k0 = blockIdx.y * 64;
    for (int i = threadIdx.x; i < 4096; i += 256) {
        int n = i & 63, k = i >> 6;
        Ts[n][k] = f2bf(W[(size_t)(k0 + k) * N + n0 + n]);
    }
    __syncthreads();
    for (int i = threadIdx.x; i < 4096; i += 256) {
        int k = i & 63, n = i >> 6;
        Wt[(size_t)(n0 + n) * K + k0 + k] = Ts[n][k];
    }
}

// ---------------- bf16 MFMA GEMM:  C[M,N] = A[M,K] · Bt[N,K]^T + bias -------
template<int OUT_BF16>
__global__ __launch_bounds__(256)
void gemm_bf16_bt(const unsigned short* __restrict__ A,
                  const unsigned short* __restrict__ Bt,
                  const float* __restrict__ bias,
                  void* __restrict__ Cout,
                  int M, int N, int K) {
    __shared__ __align__(16) unsigned short As[4096];
    __shared__ __align__(16) unsigned short Bs[4096];

    const int tid  = threadIdx.x;
    const int lane = tid & 63;
    const int c    = lane & 15;
    const int quad = lane >> 4;
    const int wave = tid >> 6;
    const int wm   = (wave >> 1) * 64;
    const int wn   = (wave & 1) * 64;
    const int bm   = blockIdx.y * 128;
    const int bn   = blockIdx.x * 128;

    const int Lp0 = tid;
    const int Lp1 = 256 + tid;
    const int L0  = Lp0 ^ ((Lp0 >> 3) & 7);
    const int L1  = Lp1 ^ ((Lp1 >> 3) & 7);
    const unsigned short* aSrc0 = A  + (size_t)(bm + (L0 >> 2)) * K + (L0 & 3) * 8;
    const unsigned short* aSrc1 = A  + (size_t)(bm + (L1 >> 2)) * K + (L1 & 3) * 8;
    const unsigned short* bSrc0 = Bt + (size_t)(bn + (L0 >> 2)) * K + (L0 & 3) * 8;
    const unsigned short* bSrc1 = Bt + (size_t)(bn + (L1 >> 2)) * K + (L1 & 3) * 8;
    unsigned short* ldsA0 = As + (tid & 0xC0) * 8;
    unsigned short* ldsA1 = As + (256 + (tid & 0xC0)) * 8;
    unsigned short* ldsB0 = Bs + (tid & 0xC0) * 8;
    unsigned short* ldsB1 = Bs + (256 + (tid & 0xC0)) * 8;

    const int xorv = (c >> 1) & 7;
    int aoff[4], boff[4];
#pragma unroll
    for (int i = 0; i < 4; i++) {
        aoff[i] = ((((wm + i * 16 + c) << 2) + quad) ^ xorv) * 8;
        boff[i] = ((((wn + i * 16 + c) << 2) + quad) ^ xorv) * 8;
    }

    f32x4 acc[4][4];
#pragma unroll
    for (int i = 0; i < 4; i++)
#pragma unroll
        for (int j = 0; j < 4; j++) acc[i][j] = (f32x4){0.f, 0.f, 0.f, 0.f};

    for (int kt = 0; kt < K; kt += 32) {
        __syncthreads();
        __builtin_amdgcn_global_load_lds((glb_void*)aSrc0, (lds_void*)ldsA0, 16, 0, 0);
        __builtin_amdgcn_global_load_lds((glb_void*)aSrc1, (lds_void*)ldsA1, 16, 0, 0);
        __builtin_amdgcn_global_load_lds((glb_void*)bSrc0, (lds_void*)ldsB0, 16, 0, 0);
        __builtin_amdgcn_global_load_lds((glb_void*)bSrc1, (lds_void*)ldsB1, 16, 0, 0);
        aSrc0 += 32; aSrc1 += 32; bSrc0 += 32; bSrc1 += 32;
        __syncthreads();

        bf16x8 af[4], bfr[4];
#pragma unroll
        for (int i = 0; i < 4; i++)
            af[i] = __builtin_bit_cast(bf16x8, *(const us8*)&As[aoff[i]]);
#pragma unroll
        for (int j = 0; j < 4; j++)
            bfr[j] = __builtin_bit_cast(bf16x8, *(const us8*)&Bs[boff[j]]);
#pragma unroll
        for (int i = 0; i < 4; i++)
#pragma unroll
            for (int j = 0; j < 4; j++)
                acc[i][j] = __builtin_amdgcn_mfma_f32_16x16x32_bf16(af[i], bfr[j], acc[i][j], 0, 0, 0);
    }

    float bs[4];
#pragma unroll
    for (int j = 0; j < 4; j++) bs[j] = bias[bn + wn + j * 16 + c];
#pragma unroll
    for (int i = 0; i < 4; i++) {
        const int gm = bm + wm + i * 16 + quad * 4;
#pragma unroll
        for (int r = 0; r < 4; r++) {
            const size_t ro = (size_t)(gm + r) * N;
#pragma unroll
            for (int j = 0; j < 4; j++) {
                const float v = acc[i][j][r] + bs[j];
                const int gn = bn + wn + j * 16 + c;
                if (OUT_BF16) ((unsigned short*)Cout)[ro + gn] = f2bf(v);
                else          ((float*)Cout)[ro + gn] = v;
            }
        }
    }
}

// ---------------- flash attention: triangular-paired Q-tiles ----------------
// Block p handles Q-tiles {p, 15-p}: every block does exactly 17 tile-works
// (perfect load balance), and each staged K/V tile feeds two Q-tiles.
// 768 blocks, XCD-swizzled: id = (bh%8) + 8*p + 64*(bh/8) -> all 8 blocks of
// a head share id%8 -> same XCD -> head's K/V L2-resident.
__global__ __launch_bounds__(256, 3)
void attn_mfma(const unsigned short* __restrict__ qkv, unsigned short* __restrict__ y) {
    __shared__ __align__(16) unsigned short Ks[64 * 72];
    __shared__ __align__(16) unsigned int   Vp[32 * 66];
    __shared__ __align__(16) unsigned short Ps[2 * 4 * 16 * 72];

    const int tid  = threadIdx.x;
    const int wave = tid >> 6;
    const int lane = tid & 63;
    const int c    = lane & 15;
    const int quad = lane >> 4;

    const int id = blockIdx.x;
    const int p  = (id >> 3) & 7;
    const int bh = (id >> 6) * 8 + (id & 7);
    const int b  = bh / H_;
    const int h  = bh - b * H_;

    const int qts[2] = {p, 15 - p};
    const int q0s[2] = {p * 64, (15 - p) * 64};

    const int RS = 3 * C_;
    const unsigned short* kbase = qkv + (size_t)b * T_ * RS + C_ + h * D_;
    const unsigned short* vbase = qkv + (size_t)b * T_ * RS + 2 * C_ + h * D_;

    // softmax in log2 domain: s' = s * 0.125 * log2(e)
    const float kSc = 0.125f * 1.44269504088896340736f;

    // ---- Q fragments to registers (A-layout: row=c, k=quad*8+j) ----
    bf16x8 qf[2][2];
#pragma unroll
    for (int t = 0; t < 2; t++) {
        const unsigned short* qrow =
            qkv + ((size_t)(b * T_ + q0s[t] + wave * 16 + c)) * RS + h * D_ + quad * 8;
        qf[t][0] = __builtin_bit_cast(bf16x8, *(const us8*)qrow);
        qf[t][1] = __builtin_bit_cast(bf16x8, *(const us8*)(qrow + 32));
    }

    // per-thread staging coords
    const int kr0 = tid >> 3, kc0 = tid & 7;
    const int vr0 = tid >> 4, vc0 = tid & 15;

    us8 kA, kB;
    ushort4 vA0, vB0, vA1, vB1;
    {
        kA = *(const us8*)(kbase + (size_t)kr0 * RS + kc0 * 8);
        kB = *(const us8*)(kbase + (size_t)(kr0 + 32) * RS + kc0 * 8);
        const unsigned short* p0 = vbase + (size_t)(2 * vr0) * RS + vc0 * 4;
        vA0 = *(const ushort4*)p0;  vB0 = *(const ushort4*)(p0 + RS);
        const unsigned short* p1 = vbase + (size_t)(2 * (vr0 + 16)) * RS + vc0 * 4;
        vA1 = *(const ushort4*)p1;  vB1 = *(const ushort4*)(p1 + RS);
    }

    f32x4 Oa[2][4];
    float m_i[2][4], l_i[2][4];
#pragma unroll
    for (int t = 0; t < 2; t++) {
#pragma unroll
        for (int d = 0; d < 4; d++) Oa[t][d] = (f32x4){0.f, 0.f, 0.f, 0.f};
#pragma unroll
        for (int r = 0; r < 4; r++) { m_i[t][r] = -INFINITY; l_i[t][r] = 0.f; }
    }

    const int ktEnd = qts[1];           // qts[1] >= qts[0]
    for (int kt = 0; kt <= ktEnd; kt++) {
        __syncthreads();
        *(us8*)&Ks[kr0 * 72 + kc0 * 8] = kA;
        *(us8*)&Ks[(kr0 + 32) * 72 + kc0 * 8] = kB;
        {
            unsigned int* d0 = &Vp[vr0 * 66 + vc0 * 4];
            d0[0] = vA0.x | ((unsigned)vB0.x << 16);
            d0[1] = vA0.y | ((unsigned)vB0.y << 16);
            d0[2] = vA0.z | ((unsigned)vB0.z << 16);
            d0[3] = vA0.w | ((unsigned)vB0.w << 16);
            unsigned int* d1 = &Vp[(vr0 + 16) * 66 + vc0 * 4];
            d1[0] = vA1.x | ((unsigned)vB1.x << 16);
            d1[1] = vA1.y | ((unsigned)vB1.y << 16);
            d1[2] = vA1.z | ((unsigned)vB1.z << 16);
            d1[3] = vA1.w | ((unsigned)vB1.w << 16);
        }
        __syncthreads();

        if (kt < ktEnd) {
            const unsigned short* kp = kbase + (size_t)((kt + 1) * 64) * RS;
            kA = *(const us8*)(kp + (size_t)kr0 * RS + kc0 * 8);
            kB = *(const us8*)(kp + (size_t)(kr0 + 32) * RS + kc0 * 8);
            const unsigned short* vp = vbase + (size_t)((kt + 1) * 64) * RS;
            const unsigned short* p0 = vp + (size_t)(2 * vr0) * RS + vc0 * 4;
            vA0 = *(const ushort4*)p0;  vB0 = *(const ushort4*)(p0 + RS);
            const unsigned short* p1 = vp + (size_t)(2 * (vr0 + 16)) * RS + vc0 * 4;
            vA1 = *(const ushort4*)p1;  vB1 = *(const ushort4*)(p1 + RS);
        }

#pragma unroll
        for (int t = 0; t < 2; t++) {
            if (kt > qts[t]) continue;   // block-uniform
            const int dRow = q0s[t] + wave * 16 - kt * 64;   // >= 0
            int nmax = (dRow + 15) >> 4; if (nmax > 3) nmax = 3;
            f32x4 s[4];
#pragma unroll
            for (int n = 0; n < 4; n++) {
                if (n <= nmax) {
                    s[n] = (f32x4){0.f, 0.f, 0.f, 0.f};
#pragma unroll
                    for (int ks = 0; ks < 2; ks++) {
                        bf16x8 bk = __builtin_bit_cast(bf16x8,
                            *(const us8*)&Ks[(n * 16 + c) * 72 + quad * 8 + ks * 32]);
                        s[n] = __builtin_amdgcn_mfma_f32_16x16x32_bf16(qf[t][ks], bk, s[n], 0, 0, 0);
                    }
                    s[n] *= kSc;
                    if (n * 16 + 15 > dRow) {
#pragma unroll
                        for (int r = 0; r < 4; r++)
                            if (n * 16 + c > dRow + quad * 4 + r) s[n][r] = -INFINITY;
                    }
                } else {
                    s[n] = (f32x4){-INFINITY, -INFINITY, -INFINITY, -INFINITY};
                }
            }

            float al[4], rs[4];
#pragma unroll
            for (int r = 0; r < 4; r++) {
                float v = fmaxf(fmaxf(s[0][r], s[1][r]), fmaxf(s[2][r], s[3][r]));
                v = fmaxf(v, __shfl_xor(v, 1, 64));
                v = fmaxf(v, __shfl_xor(v, 2, 64));
                v = fmaxf(v, __shfl_xor(v, 4, 64));
                v = fmaxf(v, __shfl_xor(v, 8, 64));
                float mn = fmaxf(m_i[t][r], v);
                al[r] = exp2f(m_i[t][r] - mn);
                m_i[t][r] = mn;
                rs[r] = 0.f;
            }
            unsigned short pb[4][4];
#pragma unroll
            for (int n = 0; n < 4; n++)
#pragma unroll
                for (int r = 0; r < 4; r++) {
                    float pv = exp2f(s[n][r] - m_i[t][r]);
                    rs[r] += pv;
                    pb[n][r] = f2bf(pv);
                }
            unsigned short* pw = &Ps[(t * 4 + wave) * 1152];
#pragma unroll
            for (int n = 0; n < 4; n++)
#pragma unroll
                for (int r = 0; r < 4; r++)
                    pw[(quad * 4 + r) * 72 + n * 16 + c] = pb[n][r];

#pragma unroll
            for (int r = 0; r < 4; r++) {
                float v = rs[r];
                v += __shfl_xor(v, 1, 64);
                v += __shfl_xor(v, 2, 64);
                v += __shfl_xor(v, 4, 64);
                v += __shfl_xor(v, 8, 64);
                l_i[t][r] = l_i[t][r] * al[r] + v;
            }
#pragma unroll
            for (int d = 0; d < 4; d++)
#pragma unroll
                for (int r = 0; r < 4; r++) Oa[t][d][r] *= al[r];

            const unsigned short* pr = &Ps[(t * 4 + wave) * 1152 + c * 72];
#pragma unroll
            for (int d = 0; d < 4; d++) {
#pragma unroll
                for (int ks = 0; ks < 2; ks++) {
                    bf16x8 ap = __builtin_bit_cast(bf16x8,
                        *(const us8*)&pr[quad * 8 + ks * 32]);
                    unsigned int bv[4];
#pragma unroll
                    for (int j2 = 0; j2 < 4; j2++)
                        bv[j2] = Vp[(ks * 16 + quad * 4 + j2) * 66 + d * 16 + c];
                    bf16x8 vb = __builtin_bit_cast(bf16x8, *(us8*)bv);
                    Oa[t][d] = __builtin_amdgcn_mfma_f32_16x16x32_bf16(ap, vb, Oa[t][d], 0, 0, 0);
                }
            }
        }
    }

#pragma unroll
    for (int t = 0; t < 2; t++) {
        unsigned short* yrow =
            y + ((size_t)(b * T_ + q0s[t] + wave * 16)) * C_ + h * D_;
#pragma unroll
        for (int r = 0; r < 4; r++) {
            float inv = 1.f / l_i[t][r];
#pragma unroll
            for (int d = 0; d < 4; d++)
                yrow[(size_t)(quad * 4 + r) * C_ + d * 16 + c] = f2bf(Oa[t][d][r] * inv);
        }
    }
}

extern "C" void kernel_launch(void* const* d_in, const int* in_sizes, int n_in,
                              void* d_out, int out_size, void* d_ws, size_t ws_size,
                              hipStream_t stream) {
    const float* x      = (const float*)d_in[0];
    const float* w_qkv  = (const float*)d_in[1];
    const float* b_qkv  = (const float*)d_in[2];
    const float* w_proj = (const float*)d_in[3];
    const float* b_proj = (const float*)d_in[4];
    float* out = (float*)d_out;

    unsigned short* xb   = (unsigned short*)d_ws;                 // [8192][768]
    unsigned short* wqT  = xb   + (size_t)B_ * T_ * C_;           // [2304][768]
    unsigned short* wpT  = wqT  + (size_t)3 * C_ * C_;            // [768][768]
    unsigned short* qkvb = wpT  + (size_t)C_ * C_;                // [8192][2304]
    unsigned short* yb   = qkvb + (size_t)B_ * T_ * 3 * C_;       // [8192][768]

    const int nx4 = B_ * T_ * C_ / 4;
    convert_bf16<<<(nx4 + 255) / 256, 256, 0, stream>>>(x, xb, nx4);
    transpose_w<<<dim3(3 * C_ / 64, C_ / 64), 256, 0, stream>>>(w_qkv, wqT, C_, 3 * C_);
    transpose_w<<<dim3(C_ / 64, C_ / 64), 256, 0, stream>>>(w_proj, wpT, C_, C_);

    // qkv = x @ w_qkv + b_qkv   (bf16 out)
    gemm_bf16_bt<1><<<dim3(3 * C_ / 128, B_ * T_ / 128), 256, 0, stream>>>(
        xb, wqT, b_qkv, qkvb, B_ * T_, 3 * C_, C_);

    // flash attention -> y (bf16), triangular-paired, XCD-swizzled
    attn_mfma<<<8 * B_ * H_, 256, 0, stream>>>(qkvb, yb);

    // out = y @ w_proj + b_proj (fp32 out)
    gemm_bf16_bt<0><<<dim3(C_ / 128, B_ * T_ / 128), 256, 0, stream>>>(
        yb, wpT, b_proj, out, B_ * T_, C_, C_);
}

// Round 6
// 201.712 us; speedup vs baseline: 21.6521x; 1.1364x over previous
//
#include <hip/hip_runtime.h>
#include <math.h>

#define B_ 8
#define T_ 1024
#define C_ 768
#define H_ 12
#define D_ 64

typedef __bf16 bf16x8 __attribute__((ext_vector_type(8)));
typedef float  f32x4  __attribute__((ext_vector_type(4)));
typedef unsigned short us8 __attribute__((ext_vector_type(8)));
typedef unsigned int   u32x4v __attribute__((ext_vector_type(4)));

typedef __attribute__((address_space(3))) void lds_void;
typedef __attribute__((address_space(1))) const void glb_void;

#define KSC 0.18033688011112043f   // 0.125 * log2(e)

__device__ __forceinline__ unsigned short f2bf(float f) {
    unsigned int u = __float_as_uint(f);
    u += 0x7fffu + ((u >> 16) & 1u);
    return (unsigned short)(u >> 16);
}

// ---------------- prep: fp32 -> bf16 elementwise (x) ------------------------
__global__ __launch_bounds__(256)
void convert_bf16(const float* __restrict__ in, unsigned short* __restrict__ out, int n4) {
    int idx = blockIdx.x * 256 + threadIdx.x;
    if (idx < n4) {
        float4 v = ((const float4*)in)[idx];
        ushort4 o;
        o.x = f2bf(v.x); o.y = f2bf(v.y); o.z = f2bf(v.z); o.w = f2bf(v.w);
        ((ushort4*)out)[idx] = o;
    }
}

// ---- prep: bias copy with Q-scale folded in --------------------------------
__global__ __launch_bounds__(256)
void scale_bias(const float* __restrict__ in, float* __restrict__ out) {
    int i = blockIdx.x * 256 + threadIdx.x;
    if (i < 3 * C_) out[i] = in[i] * (i < C_ ? KSC : 1.f);
}

// ---- prep: W[K][N] fp32 -> Wt[N][K] bf16, scaling rows n < nlim by qs ------
__global__ __launch_bounds__(256)
void transpose_w(const float* __restrict__ W, unsigned short* __restrict__ Wt,
                 int K, int N, int nlim, float qs) {
    __shared__ unsigned short Ts[64][65];
    const int n0 = blockIdx.x * 64, k0 = blockIdx.y * 64;
    for (int i = threadIdx.x; i < 4096; i += 256) {
        int n = i & 63, k = i >> 6;
        float sc = (n0 + n < nlim) ? qs : 1.f;
        Ts[n][k] = f2bf(W[(size_t)(k0 + k) * N + n0 + n] * sc);
    }
    __syncthreads();
    for (int i = threadIdx.x; i < 4096; i += 256) {
        int k = i & 63, n = i >> 6;
        Wt[(size_t)(n0 + n) * K + k0 + k] = Ts[n][k];
    }
}

// ---------------- bf16 MFMA GEMM:  C[M,N] = A[M,K] · Bt[N,K]^T + bias -------
template<int OUT_BF16>
__global__ __launch_bounds__(256)
void gemm_bf16_bt(const unsigned short* __restrict__ A,
                  const unsigned short* __restrict__ Bt,
                  const float* __restrict__ bias,
                  void* __restrict__ Cout,
                  int M, int N, int K) {
    __shared__ __align__(16) unsigned short As[4096];
    __shared__ __align__(16) unsigned short Bs[4096];

    const int tid  = threadIdx.x;
    const int lane = tid & 63;
    const int c    = lane & 15;
    const int quad = lane >> 4;
    const int wave = tid >> 6;
    const int wm   = (wave >> 1) * 64;
    const int wn   = (wave & 1) * 64;
    const int bm   = blockIdx.y * 128;
    const int bn   = blockIdx.x * 128;

    const int Lp0 = tid;
    const int Lp1 = 256 + tid;
    const int L0  = Lp0 ^ ((Lp0 >> 3) & 7);
    const int L1  = Lp1 ^ ((Lp1 >> 3) & 7);
    const unsigned short* aSrc0 = A  + (size_t)(bm + (L0 >> 2)) * K + (L0 & 3) * 8;
    const unsigned short* aSrc1 = A  + (size_t)(bm + (L1 >> 2)) * K + (L1 & 3) * 8;
    const unsigned short* bSrc0 = Bt + (size_t)(bn + (L0 >> 2)) * K + (L0 & 3) * 8;
    const unsigned short* bSrc1 = Bt + (size_t)(bn + (L1 >> 2)) * K + (L1 & 3) * 8;
    unsigned short* ldsA0 = As + (tid & 0xC0) * 8;
    unsigned short* ldsA1 = As + (256 + (tid & 0xC0)) * 8;
    unsigned short* ldsB0 = Bs + (tid & 0xC0) * 8;
    unsigned short* ldsB1 = Bs + (256 + (tid & 0xC0)) * 8;

    const int xorv = (c >> 1) & 7;
    int aoff[4], boff[4];
#pragma unroll
    for (int i = 0; i < 4; i++) {
        aoff[i] = ((((wm + i * 16 + c) << 2) + quad) ^ xorv) * 8;
        boff[i] = ((((wn + i * 16 + c) << 2) + quad) ^ xorv) * 8;
    }

    f32x4 acc[4][4];
#pragma unroll
    for (int i = 0; i < 4; i++)
#pragma unroll
        for (int j = 0; j < 4; j++) acc[i][j] = (f32x4){0.f, 0.f, 0.f, 0.f};

    for (int kt = 0; kt < K; kt += 32) {
        __syncthreads();
        __builtin_amdgcn_global_load_lds((glb_void*)aSrc0, (lds_void*)ldsA0, 16, 0, 0);
        __builtin_amdgcn_global_load_lds((glb_void*)aSrc1, (lds_void*)ldsA1, 16, 0, 0);
        __builtin_amdgcn_global_load_lds((glb_void*)bSrc0, (lds_void*)ldsB0, 16, 0, 0);
        __builtin_amdgcn_global_load_lds((glb_void*)bSrc1, (lds_void*)ldsB1, 16, 0, 0);
        aSrc0 += 32; aSrc1 += 32; bSrc0 += 32; bSrc1 += 32;
        __syncthreads();

        bf16x8 af[4], bfr[4];
#pragma unroll
        for (int i = 0; i < 4; i++)
            af[i] = __builtin_bit_cast(bf16x8, *(const us8*)&As[aoff[i]]);
#pragma unroll
        for (int j = 0; j < 4; j++)
            bfr[j] = __builtin_bit_cast(bf16x8, *(const us8*)&Bs[boff[j]]);
#pragma unroll
        for (int i = 0; i < 4; i++)
#pragma unroll
            for (int j = 0; j < 4; j++)
                acc[i][j] = __builtin_amdgcn_mfma_f32_16x16x32_bf16(af[i], bfr[j], acc[i][j], 0, 0, 0);
    }

    float bs[4];
#pragma unroll
    for (int j = 0; j < 4; j++) bs[j] = bias[bn + wn + j * 16 + c];
#pragma unroll
    for (int i = 0; i < 4; i++) {
        const int gm = bm + wm + i * 16 + quad * 4;
#pragma unroll
        for (int r = 0; r < 4; r++) {
            const size_t ro = (size_t)(gm + r) * N;
#pragma unroll
            for (int j = 0; j < 4; j++) {
                const float v = acc[i][j][r] + bs[j];
                const int gn = bn + wn + j * 16 + c;
                if (OUT_BF16) ((unsigned short*)Cout)[ro + gn] = f2bf(v);
                else          ((float*)Cout)[ro + gn] = v;
            }
        }
    }
}

// key k -> permuted LDS row, chosen so S^T output lands in PV A-frag layout
__device__ __forceinline__ int sigmaK(int k) {
    return 16 * (2 * (k >> 5) + ((k >> 2) & 1)) + 4 * ((k >> 3) & 3) + (k & 3);
}

// ---------------- flash attention: S^T trick, in-register P -----------------
// S^T = K·Q^T (operand swap): lane holds one query column (q = lane&15).
// Permuted K staging makes S^T C-layout == PV A-frag layout per lane -> P
// never leaves registers. Fixed-max softmax (scores bounded; exp2 via HW).
// Q pre-scaled by 0.125*log2e at weight-prep. Triangular pairing + XCD swizzle.
__global__ __launch_bounds__(256, 3)
void attn_mfma(const unsigned short* __restrict__ qkv, unsigned short* __restrict__ y) {
    __shared__ __align__(16) unsigned short Ks[64 * 72];   // permuted rows, pad 72
    __shared__ __align__(16) unsigned int   Vt[64 * 36];   // [d][kpair], pad 36

    const int tid  = threadIdx.x;
    const int wave = tid >> 6;
    const int lane = tid & 63;
    const int c    = lane & 15;
    const int quad = lane >> 4;

    const int id = blockIdx.x;
    const int p  = (id >> 3) & 7;
    const int bh = (id >> 6) * 8 + (id & 7);
    const int b  = bh / H_;
    const int h  = bh - b * H_;

    const int qts[2] = {p, 15 - p};
    const int q0s[2] = {p * 64, (15 - p) * 64};

    const int RS = 3 * C_;
    const unsigned short* kbase = qkv + (size_t)b * T_ * RS + C_ + h * D_;
    const unsigned short* vbase = qkv + (size_t)b * T_ * RS + 2 * C_ + h * D_;

    // ---- Q fragments (B-operand of S^T): lane (c,quad) = Q[q=c][d=quad*8+j]
    bf16x8 qf[2][2];
#pragma unroll
    for (int t = 0; t < 2; t++) {
        const unsigned short* qrow =
            qkv + ((size_t)(b * T_ + q0s[t] + wave * 16 + c)) * RS + h * D_ + quad * 8;
        qf[t][0] = __builtin_bit_cast(bf16x8, *(const us8*)qrow);
        qf[t][1] = __builtin_bit_cast(bf16x8, *(const us8*)(qrow + 32));
    }

    // staging coords
    const int kr0 = tid >> 3, kc0 = tid & 7;          // K: rows kr0, kr0+32, 16B chunk kc0
    const int sK0 = sigmaK(kr0) * 72 + kc0 * 8;
    const int sK1 = sigmaK(kr0 + 32) * 72 + kc0 * 8;
    const int dg  = tid >> 4, kp0 = tid & 15;         // V: d-cols dg*4..+3, kpairs kp0, kp0+16

    us8 kA, kB;
    ushort4 vA0, vB0, vA1, vB1;
    {
        kA = *(const us8*)(kbase + (size_t)kr0 * RS + kc0 * 8);
        kB = *(const us8*)(kbase + (size_t)(kr0 + 32) * RS + kc0 * 8);
        const unsigned short* p0 = vbase + (size_t)(2 * kp0) * RS + dg * 4;
        vA0 = *(const ushort4*)p0;  vB0 = *(const ushort4*)(p0 + RS);
        const unsigned short* p1 = vbase + (size_t)(2 * (kp0 + 16)) * RS + dg * 4;
        vA1 = *(const ushort4*)p1;  vB1 = *(const ushort4*)(p1 + RS);
    }

    f32x4 Oa[2][4];
    float l_lane[2] = {0.f, 0.f};
#pragma unroll
    for (int t = 0; t < 2; t++)
#pragma unroll
        for (int d = 0; d < 4; d++) Oa[t][d] = (f32x4){0.f, 0.f, 0.f, 0.f};

    const int ktEnd = qts[1];
    for (int kt = 0; kt <= ktEnd; kt++) {
        __syncthreads();
        *(us8*)&Ks[sK0] = kA;
        *(us8*)&Ks[sK1] = kB;
        {
            unsigned int* v0 = &Vt[(dg * 4) * 36 + kp0];
            v0[0]   = vA0.x | ((unsigned)vB0.x << 16);
            v0[36]  = vA0.y | ((unsigned)vB0.y << 16);
            v0[72]  = vA0.z | ((unsigned)vB0.z << 16);
            v0[108] = vA0.w | ((unsigned)vB0.w << 16);
            unsigned int* v1 = v0 + 16;
            v1[0]   = vA1.x | ((unsigned)vB1.x << 16);
            v1[36]  = vA1.y | ((unsigned)vB1.y << 16);
            v1[72]  = vA1.z | ((unsigned)vB1.z << 16);
            v1[108] = vA1.w | ((unsigned)vB1.w << 16);
        }
        __syncthreads();

        if (kt < ktEnd) {
            const unsigned short* kp = kbase + (size_t)((kt + 1) * 64) * RS;
            kA = *(const us8*)(kp + (size_t)kr0 * RS + kc0 * 8);
            kB = *(const us8*)(kp + (size_t)(kr0 + 32) * RS + kc0 * 8);
            const unsigned short* vp = vbase + (size_t)((kt + 1) * 64) * RS;
            const unsigned short* p0 = vp + (size_t)(2 * kp0) * RS + dg * 4;
            vA0 = *(const ushort4*)p0;  vB0 = *(const ushort4*)(p0 + RS);
            const unsigned short* p1 = vp + (size_t)(2 * (kp0 + 16)) * RS + dg * 4;
            vA1 = *(const ushort4*)p1;  vB1 = *(const ushort4*)(p1 + RS);
        }

        // K A-fragments: shared by both paired Q-tiles
        bf16x8 kf[4][2];
#pragma unroll
        for (int nb = 0; nb < 4; nb++) {
#pragma unroll
            for (int ks = 0; ks < 2; ks++)
                kf[nb][ks] = __builtin_bit_cast(bf16x8,
                    *(const us8*)&Ks[(nb * 16 + c) * 72 + quad * 8 + ks * 32]);
        }

#pragma unroll
        for (int t = 0; t < 2; t++) {
            if (kt > qts[t]) continue;            // block-uniform
            const bool diag = (kt == qts[t]);
            const int nbmax = diag ? ((wave >= 2) ? 3 : 1) : 3;

            // S^T: rows = keys (permuted), cols = queries (q = c)
            f32x4 sv[4];
#pragma unroll
            for (int nb = 0; nb < 4; nb++) {
                if (nb <= nbmax) {
                    f32x4 z = (f32x4){0.f, 0.f, 0.f, 0.f};
                    z = __builtin_amdgcn_mfma_f32_16x16x32_bf16(kf[nb][0], qf[t][0], z, 0, 0, 0);
                    sv[nb] = __builtin_amdgcn_mfma_f32_16x16x32_bf16(kf[nb][1], qf[t][1], z, 0, 0, 0);
                }
            }
            if (diag) {
                const int qloc = wave * 16 + c;
#pragma unroll
                for (int nb = 0; nb < 4; nb++) {
                    if (nb <= nbmax) {
                        const int kb = 32 * (nb >> 1) + 4 * (nb & 1) + 8 * quad;
#pragma unroll
                        for (int r = 0; r < 4; r++)
                            if (kb + r > qloc) sv[nb][r] = -INFINITY;
                    }
                }
            }

            // softmax (fixed max): p = exp2(s); accumulate l per-lane; pack P
            float rsum = 0.f;
            unsigned int pd[4][2];
#pragma unroll
            for (int nb = 0; nb < 4; nb++) {
                if (nb <= nbmax) {
                    float p0 = __builtin_amdgcn_exp2f(sv[nb][0]);
                    float p1 = __builtin_amdgcn_exp2f(sv[nb][1]);
                    float p2 = __builtin_amdgcn_exp2f(sv[nb][2]);
                    float p3 = __builtin_amdgcn_exp2f(sv[nb][3]);
                    rsum += (p0 + p1) + (p2 + p3);
                    unsigned u0 = __float_as_uint(p0) + 0x8000u;
                    unsigned u1 = __float_as_uint(p1) + 0x8000u;
                    unsigned u2 = __float_as_uint(p2) + 0x8000u;
                    unsigned u3 = __float_as_uint(p3) + 0x8000u;
                    pd[nb][0] = (u0 >> 16) | (u1 & 0xffff0000u);
                    pd[nb][1] = (u2 >> 16) | (u3 & 0xffff0000u);
                } else {
                    pd[nb][0] = 0u; pd[nb][1] = 0u;
                }
            }
            l_lane[t] += rsum;

            // PV: A-frags are the in-register packed P dwords
            bf16x8 ap0 = __builtin_bit_cast(bf16x8,
                (u32x4v){pd[0][0], pd[0][1], pd[1][0], pd[1][1]});
            bf16x8 ap1 = __builtin_bit_cast(bf16x8,
                (u32x4v){pd[2][0], pd[2][1], pd[3][0], pd[3][1]});
#pragma unroll
            for (int dd = 0; dd < 4; dd++) {
                const unsigned int* vrow = &Vt[(dd * 16 + c) * 36 + quad * 4];
                bf16x8 vb0 = __builtin_bit_cast(bf16x8, *(const u32x4v*)vrow);
                bf16x8 vb1 = __builtin_bit_cast(bf16x8, *(const u32x4v*)(vrow + 16));
                Oa[t][dd] = __builtin_amdgcn_mfma_f32_16x16x32_bf16(ap0, vb0, Oa[t][dd], 0, 0, 0);
                Oa[t][dd] = __builtin_amdgcn_mfma_f32_16x16x32_bf16(ap1, vb1, Oa[t][dd], 0, 0, 0);
            }
        }
    }

    // epilogue: reduce l across quads, divide, store
#pragma unroll
    for (int t = 0; t < 2; t++) {
        float lr = l_lane[t];
        lr += __shfl_xor(lr, 16, 64);
        lr += __shfl_xor(lr, 32, 64);
        unsigned short* yrow =
            y + ((size_t)(b * T_ + q0s[t] + wave * 16)) * C_ + h * D_;
#pragma unroll
        for (int r = 0; r < 4; r++) {
            float lq  = __shfl(lr, quad * 4 + r, 64);
            float inv = 1.f / lq;
#pragma unroll
            for (int dd = 0; dd < 4; dd++)
                yrow[(size_t)(quad * 4 + r) * C_ + dd * 16 + c] = f2bf(Oa[t][dd][r] * inv);
        }
    }
}

extern "C" void kernel_launch(void* const* d_in, const int* in_sizes, int n_in,
                              void* d_out, int out_size, void* d_ws, size_t ws_size,
                              hipStream_t stream) {
    const float* x      = (const float*)d_in[0];
    const float* w_qkv  = (const float*)d_in[1];
    const float* b_qkv  = (const float*)d_in[2];
    const float* w_proj = (const float*)d_in[3];
    const float* b_proj = (const float*)d_in[4];
    float* out = (float*)d_out;

    unsigned short* xb   = (unsigned short*)d_ws;                 // [8192][768]
    unsigned short* wqT  = xb   + (size_t)B_ * T_ * C_;           // [2304][768]
    unsigned short* wpT  = wqT  + (size_t)3 * C_ * C_;            // [768][768]
    unsigned short* qkvb = wpT  + (size_t)C_ * C_;                // [8192][2304]
    unsigned short* yb   = qkvb + (size_t)B_ * T_ * 3 * C_;       // [8192][768]
    float*          bqs  = (float*)(yb + (size_t)B_ * T_ * C_);   // [2304]

    const int nx4 = B_ * T_ * C_ / 4;
    convert_bf16<<<(nx4 + 255) / 256, 256, 0, stream>>>(x, xb, nx4);
    scale_bias<<<(3 * C_ + 255) / 256, 256, 0, stream>>>(b_qkv, bqs);
    transpose_w<<<dim3(3 * C_ / 64, C_ / 64), 256, 0, stream>>>(w_qkv, wqT, C_, 3 * C_, C_, KSC);
    transpose_w<<<dim3(C_ / 64, C_ / 64), 256, 0, stream>>>(w_proj, wpT, C_, C_, 0, 1.f);

    // qkv = x @ w_qkv + b_qkv   (Q pre-scaled; bf16 out)
    gemm_bf16_bt<1><<<dim3(3 * C_ / 128, B_ * T_ / 128), 256, 0, stream>>>(
        xb, wqT, bqs, qkvb, B_ * T_, 3 * C_, C_);

    // flash attention -> y (bf16)
    attn_mfma<<<8 * B_ * H_, 256, 0, stream>>>(qkvb, yb);

    // out = y @ w_proj + b_proj (fp32 out)
    gemm_bf16_bt<0><<<dim3(C_ / 128, B_ * T_ / 128), 256, 0, stream>>>(
        yb, wpT, b_proj, out, B_ * T_, C_, C_);
}

// Round 7
// 189.736 us; speedup vs baseline: 23.0188x; 1.0631x over previous
//
#include <hip/hip_runtime.h>
#include <math.h>

#define B_ 8
#define T_ 1024
#define C_ 768
#define H_ 12
#define D_ 64

typedef __bf16 bf16x8 __attribute__((ext_vector_type(8)));
typedef float  f32x4  __attribute__((ext_vector_type(4)));
typedef unsigned short us8 __attribute__((ext_vector_type(8)));
typedef unsigned int   u32x4v __attribute__((ext_vector_type(4)));

typedef __attribute__((address_space(3))) void lds_void;
typedef __attribute__((address_space(1))) const void glb_void;

#define KSC 0.18033688011112043f   // 0.125 * log2(e)

__device__ __forceinline__ unsigned short f2bf(float f) {
    unsigned int u = __float_as_uint(f);
    u += 0x7fffu + ((u >> 16) & 1u);
    return (unsigned short)(u >> 16);
}

// ---------------- merged prep: x->bf16, w transposes (+Q scale), bias -------
__global__ __launch_bounds__(256)
void prep_all(const float* __restrict__ x, const float* __restrict__ w_qkv,
              const float* __restrict__ b_qkv, const float* __restrict__ w_proj,
              unsigned short* __restrict__ xb, unsigned short* __restrict__ wqT,
              unsigned short* __restrict__ wpT, float* __restrict__ bqs) {
    __shared__ unsigned short Ts[64][65];
    const int id  = blockIdx.x;
    const int tid = threadIdx.x;
    if (id < 6144) {                       // x fp32 -> bf16, float4 granules
        int idx = id * 256 + tid;
        float4 v = ((const float4*)x)[idx];
        ushort4 o;
        o.x = f2bf(v.x); o.y = f2bf(v.y); o.z = f2bf(v.z); o.w = f2bf(v.w);
        ((ushort4*)xb)[idx] = o;
        return;
    }
    if (id < 6729) {
        const float* W; unsigned short* Wt; int N, nlim, t2;
        if (id < 6576) { t2 = id - 6144; W = w_qkv;  Wt = wqT; N = 3 * C_; nlim = C_;
            ;
        } else if (id < 6720) { t2 = id - 6576; W = w_proj; Wt = wpT; N = C_; nlim = 0;
        } else {                              // bias with Q-scale
            int i = (id - 6720) * 256 + tid;
            if (i < 3 * C_) bqs[i] = b_qkv[i] * (i < C_ ? KSC : 1.f);
            return;
        }
        const int ntiles = N / 64;
        const int n0 = (t2 % ntiles) * 64, k0 = (t2 / ntiles) * 64;
        for (int i = tid; i < 4096; i += 256) {
            int n = i & 63, k = i >> 6;
            float sc = (n0 + n < nlim) ? KSC : 1.f;
            Ts[n][k] = f2bf(W[(size_t)(k0 + k) * N + n0 + n] * sc);
        }
        __syncthreads();
        for (int i = tid; i < 4096; i += 256) {
            int k = i & 63, n = i >> 6;
            Wt[(size_t)(n0 + n) * 768 + k0 + k] = Ts[n][k];
        }
    }
}

// ---------------- bf16 MFMA GEMM:  C[M,N] = A[M,K] · Bt[N,K]^T + bias -------
// 128x128 tile, BK=64 (12 rounds at K=768 -> half the barrier drains).
// LDS tile = 128 rows x 8 16B-cells; cell (r,kc) stored at r*8 + (kc^(r&7)):
// staging via global_load_lds stays lane-contiguous, frag ds_read_b128s are
// evenly spread (4 lanes/bank-set). blockIdx.x = M so same-m blocks share
// id%8 -> same XCD -> A-slice L2-resident.
template<int OUT_BF16>
__global__ __launch_bounds__(256)
void gemm_bf16_bt(const unsigned short* __restrict__ A,
                  const unsigned short* __restrict__ Bt,
                  const float* __restrict__ bias,
                  void* __restrict__ Cout,
                  int M, int N, int K) {
    __shared__ __align__(16) unsigned short As[8192];
    __shared__ __align__(16) unsigned short Bs[8192];

    const int tid  = threadIdx.x;
    const int lane = tid & 63;
    const int c    = lane & 15;
    const int quad = lane >> 4;
    const int wave = tid >> 6;
    const int wm   = (wave >> 1) * 64;
    const int wn   = (wave & 1) * 64;
    const int bm   = blockIdx.x * 128;   // M fast -> XCD locality on A
    const int bn   = blockIdx.y * 128;

    const unsigned short* aS[4];
    const unsigned short* bS[4];
#pragma unroll
    for (int p = 0; p < 4; p++) {
        int Lp = p * 256 + tid;
        int L  = Lp ^ ((Lp >> 3) & 7);
        aS[p] = A  + (size_t)(bm + (L >> 3)) * K + (L & 7) * 8;
        bS[p] = Bt + (size_t)(bn + (L >> 3)) * K + (L & 7) * 8;
    }
    const int wb = (tid & 0xC0) * 8;     // wave-uniform LDS base (ushort units)

    int aoff[4][2], boff[4][2];
#pragma unroll
    for (int i = 0; i < 4; i++)
#pragma unroll
        for (int ks = 0; ks < 2; ks++) {
            const int kcA = (ks * 4 + quad) ^ (c & 7);
            aoff[i][ks] = ((wm + i * 16 + c) * 8 + kcA) * 8;
            boff[i][ks] = ((wn + i * 16 + c) * 8 + kcA) * 8;
        }

    f32x4 acc[4][4];
#pragma unroll
    for (int i = 0; i < 4; i++)
#pragma unroll
        for (int j = 0; j < 4; j++) acc[i][j] = (f32x4){0.f, 0.f, 0.f, 0.f};

    for (int kt = 0; kt < K; kt += 64) {
        __syncthreads();
#pragma unroll
        for (int p = 0; p < 4; p++) {
            __builtin_amdgcn_global_load_lds((glb_void*)aS[p],
                (lds_void*)(As + p * 2048 + wb), 16, 0, 0);
            __builtin_amdgcn_global_load_lds((glb_void*)bS[p],
                (lds_void*)(Bs + p * 2048 + wb), 16, 0, 0);
            aS[p] += 64; bS[p] += 64;
        }
        __syncthreads();
#pragma unroll
        for (int ks = 0; ks < 2; ks++) {
            bf16x8 af[4], bfr[4];
#pragma unroll
            for (int i = 0; i < 4; i++)
                af[i] = __builtin_bit_cast(bf16x8, *(const us8*)&As[aoff[i][ks]]);
#pragma unroll
            for (int j = 0; j < 4; j++)
                bfr[j] = __builtin_bit_cast(bf16x8, *(const us8*)&Bs[boff[j][ks]]);
#pragma unroll
            for (int i = 0; i < 4; i++)
#pragma unroll
                for (int j = 0; j < 4; j++)
                    acc[i][j] = __builtin_amdgcn_mfma_f32_16x16x32_bf16(af[i], bfr[j], acc[i][j], 0, 0, 0);
        }
    }

    float bs[4];
#pragma unroll
    for (int j = 0; j < 4; j++) bs[j] = bias[bn + wn + j * 16 + c];
#pragma unroll
    for (int i = 0; i < 4; i++) {
        const int gm = bm + wm + i * 16 + quad * 4;
#pragma unroll
        for (int r = 0; r < 4; r++) {
            const size_t ro = (size_t)(gm + r) * N;
#pragma unroll
            for (int j = 0; j < 4; j++) {
                const float v = acc[i][j][r] + bs[j];
                const int gn = bn + wn + j * 16 + c;
                if (OUT_BF16) ((unsigned short*)Cout)[ro + gn] = f2bf(v);
                else          ((float*)Cout)[ro + gn] = v;
            }
        }
    }
}

// key k -> permuted LDS row, chosen so S^T output lands in PV A-frag layout
__device__ __forceinline__ int sigmaK(int k) {
    return 16 * (2 * (k >> 5) + ((k >> 2) & 1)) + 4 * ((k >> 3) & 3) + (k & 3);
}

// ---------------- flash attention: S^T trick, in-register P -----------------
// l computed by a ones-column MFMA: D[q][*] = sum_k P[q][k] lands per-lane in
// the exact C-layout rows the epilogue divides -> zero cross-lane reduction.
__global__ __launch_bounds__(256, 3)
void attn_mfma(const unsigned short* __restrict__ qkv, unsigned short* __restrict__ y) {
    __shared__ __align__(16) unsigned short Ks[64 * 72];   // permuted rows, pad 72
    __shared__ __align__(16) unsigned int   Vt[64 * 36];   // [d][kpair], pad 36

    const int tid  = threadIdx.x;
    const int wave = tid >> 6;
    const int lane = tid & 63;
    const int c    = lane & 15;
    const int quad = lane >> 4;

    const int id = blockIdx.x;
    const int p  = (id >> 3) & 7;
    const int bh = (id >> 6) * 8 + (id & 7);
    const int b  = bh / H_;
    const int h  = bh - b * H_;

    const int qts[2] = {p, 15 - p};
    const int q0s[2] = {p * 64, (15 - p) * 64};

    const int RS = 3 * C_;
    const unsigned short* kbase = qkv + (size_t)b * T_ * RS + C_ + h * D_;
    const unsigned short* vbase = qkv + (size_t)b * T_ * RS + 2 * C_ + h * D_;

    const u32x4v onesu = {0x3F803F80u, 0x3F803F80u, 0x3F803F80u, 0x3F803F80u};
    const bf16x8 onesf = __builtin_bit_cast(bf16x8, onesu);

    // ---- Q fragments (B-operand of S^T): lane (c,quad) = Q[q=c][d=quad*8+j]
    bf16x8 qf[2][2];
#pragma unroll
    for (int t = 0; t < 2; t++) {
        const unsigned short* qrow =
            qkv + ((size_t)(b * T_ + q0s[t] + wave * 16 + c)) * RS + h * D_ + quad * 8;
        qf[t][0] = __builtin_bit_cast(bf16x8, *(const us8*)qrow);
        qf[t][1] = __builtin_bit_cast(bf16x8, *(const us8*)(qrow + 32));
    }

    // staging coords
    const int kr0 = tid >> 3, kc0 = tid & 7;
    const int sK0 = sigmaK(kr0) * 72 + kc0 * 8;
    const int sK1 = sigmaK(kr0 + 32) * 72 + kc0 * 8;
    const int dg  = tid >> 4, kp0 = tid & 15;

    us8 kA, kB;
    ushort4 vA0, vB0, vA1, vB1;
    {
        kA = *(const us8*)(kbase + (size_t)kr0 * RS + kc0 * 8);
        kB = *(const us8*)(kbase + (size_t)(kr0 + 32) * RS + kc0 * 8);
        const unsigned short* p0 = vbase + (size_t)(2 * kp0) * RS + dg * 4;
        vA0 = *(const ushort4*)p0;  vB0 = *(const ushort4*)(p0 + RS);
        const unsigned short* p1 = vbase + (size_t)(2 * (kp0 + 16)) * RS + dg * 4;
        vA1 = *(const ushort4*)p1;  vB1 = *(const ushort4*)(p1 + RS);
    }

    f32x4 Oa[2][4];
    f32x4 Ol[2];
#pragma unroll
    for (int t = 0; t < 2; t++) {
        Ol[t] = (f32x4){0.f, 0.f, 0.f, 0.f};
#pragma unroll
        for (int d = 0; d < 4; d++) Oa[t][d] = (f32x4){0.f, 0.f, 0.f, 0.f};
    }

    const int ktEnd = qts[1];
    for (int kt = 0; kt <= ktEnd; kt++) {
        __syncthreads();
        *(us8*)&Ks[sK0] = kA;
        *(us8*)&Ks[sK1] = kB;
        {
            unsigned int* v0 = &Vt[(dg * 4) * 36 + kp0];
            v0[0]   = vA0.x | ((unsigned)vB0.x << 16);
            v0[36]  = vA0.y | ((unsigned)vB0.y << 16);
            v0[72]  = vA0.z | ((unsigned)vB0.z << 16);
            v0[108] = vA0.w | ((unsigned)vB0.w << 16);
            unsigned int* v1 = v0 + 16;
            v1[0]   = vA1.x | ((unsigned)vB1.x << 16);
            v1[36]  = vA1.y | ((unsigned)vB1.y << 16);
            v1[72]  = vA1.z | ((unsigned)vB1.z << 16);
            v1[108] = vA1.w | ((unsigned)vB1.w << 16);
        }
        __syncthreads();

        if (kt < ktEnd) {
            const unsigned short* kp = kbase + (size_t)((kt + 1) * 64) * RS;
            kA = *(const us8*)(kp + (size_t)kr0 * RS + kc0 * 8);
            kB = *(const us8*)(kp + (size_t)(kr0 + 32) * RS + kc0 * 8);
            const unsigned short* vp = vbase + (size_t)((kt + 1) * 64) * RS;
            const unsigned short* p0 = vp + (size_t)(2 * kp0) * RS + dg * 4;
            vA0 = *(const ushort4*)p0;  vB0 = *(const ushort4*)(p0 + RS);
            const unsigned short* p1 = vp + (size_t)(2 * (kp0 + 16)) * RS + dg * 4;
            vA1 = *(const ushort4*)p1;  vB1 = *(const ushort4*)(p1 + RS);
        }

        // K A-fragments: shared by both paired Q-tiles
        bf16x8 kf[4][2];
#pragma unroll
        for (int nb = 0; nb < 4; nb++) {
#pragma unroll
            for (int ks = 0; ks < 2; ks++)
                kf[nb][ks] = __builtin_bit_cast(bf16x8,
                    *(const us8*)&Ks[(nb * 16 + c) * 72 + quad * 8 + ks * 32]);
        }

#pragma unroll
        for (int t = 0; t < 2; t++) {
            if (kt > qts[t]) continue;            // block-uniform
            const bool diag = (kt == qts[t]);
            const bool doHi = !diag || (wave >= 2);   // keys 32-63 live?
            const int nbmax = diag ? ((wave >= 2) ? 3 : 1) : 3;

            f32x4 sv[4];
#pragma unroll
            for (int nb = 0; nb < 4; nb++) {
                if (nb <= nbmax) {
                    f32x4 z = (f32x4){0.f, 0.f, 0.f, 0.f};
                    z = __builtin_amdgcn_mfma_f32_16x16x32_bf16(kf[nb][0], qf[t][0], z, 0, 0, 0);
                    sv[nb] = __builtin_amdgcn_mfma_f32_16x16x32_bf16(kf[nb][1], qf[t][1], z, 0, 0, 0);
                }
            }
            if (diag) {
                const int qloc = wave * 16 + c;
#pragma unroll
                for (int nb = 0; nb < 4; nb++) {
                    if (nb <= nbmax) {
                        const int kb = 32 * (nb >> 1) + 4 * (nb & 1) + 8 * quad;
#pragma unroll
                        for (int r = 0; r < 4; r++)
                            if (kb + r > qloc) sv[nb][r] = -INFINITY;
                    }
                }
            }

            // p = exp2(s); pack to bf16 pairs (RNE)
            unsigned int pd[4][2];
#pragma unroll
            for (int nb = 0; nb < 4; nb++) {
                if (nb <= nbmax) {
                    float p0 = __builtin_amdgcn_exp2f(sv[nb][0]);
                    float p1 = __builtin_amdgcn_exp2f(sv[nb][1]);
                    float p2 = __builtin_amdgcn_exp2f(sv[nb][2]);
                    float p3 = __builtin_amdgcn_exp2f(sv[nb][3]);
                    unsigned u0 = __float_as_uint(p0) + 0x8000u;
                    unsigned u1 = __float_as_uint(p1) + 0x8000u;
                    unsigned u2 = __float_as_uint(p2) + 0x8000u;
                    unsigned u3 = __float_as_uint(p3) + 0x8000u;
                    pd[nb][0] = (u0 >> 16) | (u1 & 0xffff0000u);
                    pd[nb][1] = (u2 >> 16) | (u3 & 0xffff0000u);
                } else {
                    pd[nb][0] = 0u; pd[nb][1] = 0u;
                }
            }

            bf16x8 ap0 = __builtin_bit_cast(bf16x8,
                (u32x4v){pd[0][0], pd[0][1], pd[1][0], pd[1][1]});
            bf16x8 ap1 = __builtin_bit_cast(bf16x8,
                (u32x4v){pd[2][0], pd[2][1], pd[3][0], pd[3][1]});

            // l via ones-column MFMA (lands in epilogue-ready C-layout)
            Ol[t] = __builtin_amdgcn_mfma_f32_16x16x32_bf16(ap0, onesf, Ol[t], 0, 0, 0);
            if (doHi)
                Ol[t] = __builtin_amdgcn_mfma_f32_16x16x32_bf16(ap1, onesf, Ol[t], 0, 0, 0);

#pragma unroll
            for (int dd = 0; dd < 4; dd++) {
                const unsigned int* vrow = &Vt[(dd * 16 + c) * 36 + quad * 4];
                bf16x8 vb0 = __builtin_bit_cast(bf16x8, *(const u32x4v*)vrow);
                Oa[t][dd] = __builtin_amdgcn_mfma_f32_16x16x32_bf16(ap0, vb0, Oa[t][dd], 0, 0, 0);
                if (doHi) {
                    bf16x8 vb1 = __builtin_bit_cast(bf16x8, *(const u32x4v*)(vrow + 16));
                    Oa[t][dd] = __builtin_amdgcn_mfma_f32_16x16x32_bf16(ap1, vb1, Oa[t][dd], 0, 0, 0);
                }
            }
        }
    }

    // epilogue: divide by l (already per-lane in correct rows), store
#pragma unroll
    for (int t = 0; t < 2; t++) {
        unsigned short* yrow =
            y + ((size_t)(b * T_ + q0s[t] + wave * 16)) * C_ + h * D_;
#pragma unroll
        for (int r = 0; r < 4; r++) {
            float inv = 1.f / Ol[t][r];
#pragma unroll
            for (int dd = 0; dd < 4; dd++)
                yrow[(size_t)(quad * 4 + r) * C_ + dd * 16 + c] = f2bf(Oa[t][dd][r] * inv);
        }
    }
}

extern "C" void kernel_launch(void* const* d_in, const int* in_sizes, int n_in,
                              void* d_out, int out_size, void* d_ws, size_t ws_size,
                              hipStream_t stream) {
    const float* x      = (const float*)d_in[0];
    const float* w_qkv  = (const float*)d_in[1];
    const float* b_qkv  = (const float*)d_in[2];
    const float* w_proj = (const float*)d_in[3];
    const float* b_proj = (const float*)d_in[4];
    float* out = (float*)d_out;

    unsigned short* xb   = (unsigned short*)d_ws;                 // [8192][768]
    unsigned short* wqT  = xb   + (size_t)B_ * T_ * C_;           // [2304][768]
    unsigned short* wpT  = wqT  + (size_t)3 * C_ * C_;            // [768][768]
    unsigned short* qkvb = wpT  + (size_t)C_ * C_;                // [8192][2304]
    unsigned short* yb   = qkvb + (size_t)B_ * T_ * 3 * C_;       // [8192][768]
    float*          bqs  = (float*)(yb + (size_t)B_ * T_ * C_);   // [2304]

    // one merged prep launch: 6144 convert + 432 + 144 transpose + 9 bias
    prep_all<<<6729, 256, 0, stream>>>(x, w_qkv, b_qkv, w_proj, xb, wqT, wpT, bqs);

    // qkv = x @ w_qkv + b_qkv   (Q pre-scaled; bf16 out). blockIdx.x = M.
    gemm_bf16_bt<1><<<dim3(B_ * T_ / 128, 3 * C_ / 128), 256, 0, stream>>>(
        xb, wqT, bqs, qkvb, B_ * T_, 3 * C_, C_);

    // flash attention -> y (bf16)
    attn_mfma<<<8 * B_ * H_, 256, 0, stream>>>(qkvb, yb);

    // out = y @ w_proj + b_proj (fp32 out). blockIdx.x = M.
    gemm_bf16_bt<0><<<dim3(B_ * T_ / 128, C_ / 128), 256, 0, stream>>>(
        yb, wpT, b_proj, out, B_ * T_, C_, C_);
}

// Round 8
// 183.337 us; speedup vs baseline: 23.8223x; 1.0349x over previous
//
#include <hip/hip_runtime.h>
#include <math.h>

#define B_ 8
#define T_ 1024
#define C_ 768
#define H_ 12
#define D_ 64

typedef __bf16 bf16x8 __attribute__((ext_vector_type(8)));
typedef float  f32x4  __attribute__((ext_vector_type(4)));
typedef unsigned short us8 __attribute__((ext_vector_type(8)));
typedef unsigned int   u32x4v __attribute__((ext_vector_type(4)));

typedef __attribute__((address_space(3))) void lds_void;
typedef __attribute__((address_space(1))) const void glb_void;

#define KSC 0.18033688011112043f   // 0.125 * log2(e)

__device__ __forceinline__ unsigned short f2bf(float f) {
    unsigned int u = __float_as_uint(f);
    u += 0x7fffu + ((u >> 16) & 1u);
    return (unsigned short)(u >> 16);
}

// ---------------- prep: weight transposes (+Q scale) + bias -----------------
// 432 w_qkv tiles, 144 w_proj tiles, 1 bias block = 577 blocks.
__global__ __launch_bounds__(256)
void prep_w(const float* __restrict__ w_qkv, const float* __restrict__ b_qkv,
            const float* __restrict__ w_proj,
            unsigned short* __restrict__ wqT, unsigned short* __restrict__ wpT,
            float* __restrict__ bqs) {
    __shared__ unsigned short Ts[64][65];
    const int id  = blockIdx.x;
    const int tid = threadIdx.x;
    if (id == 576) {                       // bias with Q-scale
        for (int i = tid; i < 3 * C_; i += 256)
            bqs[i] = b_qkv[i] * (i < C_ ? KSC : 1.f);
        return;
    }
    const float* W; unsigned short* Wt; int N, nlim, t2;
    if (id < 432) { t2 = id;       W = w_qkv;  Wt = wqT; N = 3 * C_; nlim = C_; }
    else          { t2 = id - 432; W = w_proj; Wt = wpT; N = C_;     nlim = 0;  }
    const int ntiles = N / 64;
    const int n0 = (t2 % ntiles) * 64, k0 = (t2 / ntiles) * 64;
    for (int i = tid; i < 4096; i += 256) {
        int n = i & 63, k = i >> 6;
        float sc = (n0 + n < nlim) ? KSC : 1.f;
        Ts[n][k] = f2bf(W[(size_t)(k0 + k) * N + n0 + n] * sc);
    }
    __syncthreads();
    for (int i = tid; i < 4096; i += 256) {
        int k = i & 63, n = i >> 6;
        Wt[(size_t)(n0 + n) * 768 + k0 + k] = Ts[n][k];
    }
}

// ---------------- pipelined bf16 MFMA GEMM:  C = A · Bt^T + bias ------------
// 128x128 tile, BK=64. A staged global->reg->LDS (converting fp32->bf16 in
// flight when A_FP32); B staged via global_load_lds into double-buffered Bs.
// All prefetches issue BEFORE the compute phase, so the vmcnt drain at the
// next round's first barrier lands after a full round of MFMA cover (the
// attn-kernel staging pattern; fixes the m97 barrier-drain stall).
// LDS cell swizzle: logical (row, kc) lives at linear (row, kc ^ (row&7)).
// blockIdx.x = M so same-m blocks share id%8 -> same XCD -> A L2-resident.
template<int A_FP32, int OUT_BF16>
__global__ __launch_bounds__(256, 3)
void gemm_pipe(const float* __restrict__ Af, const unsigned short* __restrict__ A16,
               const unsigned short* __restrict__ Bt, const float* __restrict__ bias,
               void* __restrict__ Cout, int M, int N, int K) {
    __shared__ __align__(16) unsigned short As[8192];        // 128 x 8 cells
    __shared__ __align__(16) unsigned short Bs[2][8192];     // double-buffered

    const int tid  = threadIdx.x;
    const int lane = tid & 63;
    const int c    = lane & 15;
    const int quad = lane >> 4;
    const int wave = tid >> 6;
    const int wm   = (wave >> 1) * 64;
    const int wn   = (wave & 1) * 64;
    const int bm   = blockIdx.x * 128;
    const int bn   = blockIdx.y * 128;

    // A: thread owns linear cells Lp = p*256+tid; content = logical cell
    // (row = Lp>>3, kc = (Lp ^ row) & 7). ds_write to linear addr (conflict-free).
    const float*          aF[4];
    const unsigned short* aH[4];
    int wAddr[4];
#pragma unroll
    for (int p = 0; p < 4; p++) {
        const int Lp = p * 256 + tid;
        const int r  = Lp >> 3;
        const int kc = (Lp ^ r) & 7;
        if (A_FP32) aF[p] = Af  + (size_t)(bm + r) * K + kc * 8;
        else        aH[p] = A16 + (size_t)(bm + r) * K + kc * 8;
        wAddr[p] = Lp * 8;
    }
    // B: global_load_lds, source pre-swizzled so linear dest holds swizzled cell
    const unsigned short* bS[4];
#pragma unroll
    for (int p = 0; p < 4; p++) {
        const int Lp = p * 256 + tid;
        const int L  = Lp ^ ((Lp >> 3) & 7);
        bS[p] = Bt + (size_t)(bn + (L >> 3)) * K + (L & 7) * 8;
    }
    const int wb = (tid & 0xC0) * 8;

    int aoff[4][2], boff[4][2];
#pragma unroll
    for (int i = 0; i < 4; i++)
#pragma unroll
        for (int ks = 0; ks < 2; ks++) {
            const int kcA = (ks * 4 + quad) ^ (c & 7);
            aoff[i][ks] = ((wm + i * 16 + c) * 8 + kcA) * 8;
            boff[i][ks] = ((wn + i * 16 + c) * 8 + kcA) * 8;
        }

    float4 a0[4], a1[4];
    us8    aR[4];
    f32x4 acc[4][4];
#pragma unroll
    for (int i = 0; i < 4; i++)
#pragma unroll
        for (int j = 0; j < 4; j++) acc[i][j] = (f32x4){0.f, 0.f, 0.f, 0.f};

    // prologue: prefetch round 0
#pragma unroll
    for (int p = 0; p < 4; p++) {
        __builtin_amdgcn_global_load_lds((glb_void*)bS[p],
            (lds_void*)(&Bs[0][0] + p * 2048 + wb), 16, 0, 0);
        bS[p] += 64;
        if (A_FP32) { a0[p] = *(const float4*)aF[p]; a1[p] = *(const float4*)(aF[p] + 4); aF[p] += 64; }
        else        { aR[p] = *(const us8*)aH[p]; aH[p] += 64; }
    }

    const int R = K >> 6;
    for (int r = 0; r < R; r++) {
        __syncthreads();        // prev round's LDS reads done; drains prefetches
#pragma unroll
        for (int p = 0; p < 4; p++) {
            us8 w;
            if (A_FP32) {
                w[0] = f2bf(a0[p].x); w[1] = f2bf(a0[p].y);
                w[2] = f2bf(a0[p].z); w[3] = f2bf(a0[p].w);
                w[4] = f2bf(a1[p].x); w[5] = f2bf(a1[p].y);
                w[6] = f2bf(a1[p].z); w[7] = f2bf(a1[p].w);
            } else w = aR[p];
            *(us8*)&As[wAddr[p]] = w;
        }
        __syncthreads();        // staging visible

        if (r + 1 < R) {        // prefetch r+1 BEFORE compute (latency covered)
#pragma unroll
            for (int p = 0; p < 4; p++) {
                __builtin_amdgcn_global_load_lds((glb_void*)bS[p],
                    (lds_void*)(&Bs[(r + 1) & 1][0] + p * 2048 + wb), 16, 0, 0);
                bS[p] += 64;
                if (A_FP32) { a0[p] = *(const float4*)aF[p]; a1[p] = *(const float4*)(aF[p] + 4); aF[p] += 64; }
                else        { aR[p] = *(const us8*)aH[p]; aH[p] += 64; }
            }
        }

        const unsigned short* bbuf = &Bs[r & 1][0];
#pragma unroll
        for (int ks = 0; ks < 2; ks++) {
            bf16x8 af[4], bfr[4];
#pragma unroll
            for (int i = 0; i < 4; i++)
                af[i] = __builtin_bit_cast(bf16x8, *(const us8*)&As[aoff[i][ks]]);
#pragma unroll
            for (int j = 0; j < 4; j++)
                bfr[j] = __builtin_bit_cast(bf16x8, *(const us8*)&bbuf[boff[j][ks]]);
#pragma unroll
            for (int i = 0; i < 4; i++)
#pragma unroll
                for (int j = 0; j < 4; j++)
                    acc[i][j] = __builtin_amdgcn_mfma_f32_16x16x32_bf16(af[i], bfr[j], acc[i][j], 0, 0, 0);
        }
    }

    float bs[4];
#pragma unroll
    for (int j = 0; j < 4; j++) bs[j] = bias[bn + wn + j * 16 + c];
#pragma unroll
    for (int i = 0; i < 4; i++) {
        const int gm = bm + wm + i * 16 + quad * 4;
#pragma unroll
        for (int r = 0; r < 4; r++) {
            const size_t ro = (size_t)(gm + r) * N;
#pragma unroll
            for (int j = 0; j < 4; j++) {
                const float v = acc[i][j][r] + bs[j];
                const int gn = bn + wn + j * 16 + c;
                if (OUT_BF16) ((unsigned short*)Cout)[ro + gn] = f2bf(v);
                else          ((float*)Cout)[ro + gn] = v;
            }
        }
    }
}

// key k -> permuted LDS row, chosen so S^T output lands in PV A-frag layout
__device__ __forceinline__ int sigmaK(int k) {
    return 16 * (2 * (k >> 5) + ((k >> 2) & 1)) + 4 * ((k >> 3) & 3) + (k & 3);
}

// ---------------- flash attention: S^T trick, in-register P -----------------
__global__ __launch_bounds__(256, 3)
void attn_mfma(const unsigned short* __restrict__ qkv, unsigned short* __restrict__ y) {
    __shared__ __align__(16) unsigned short Ks[64 * 72];
    __shared__ __align__(16) unsigned int   Vt[64 * 36];

    const int tid  = threadIdx.x;
    const int wave = tid >> 6;
    const int lane = tid & 63;
    const int c    = lane & 15;
    const int quad = lane >> 4;

    const int id = blockIdx.x;
    const int p  = (id >> 3) & 7;
    const int bh = (id >> 6) * 8 + (id & 7);
    const int b  = bh / H_;
    const int h  = bh - b * H_;

    const int qts[2] = {p, 15 - p};
    const int q0s[2] = {p * 64, (15 - p) * 64};

    const int RS = 3 * C_;
    const unsigned short* kbase = qkv + (size_t)b * T_ * RS + C_ + h * D_;
    const unsigned short* vbase = qkv + (size_t)b * T_ * RS + 2 * C_ + h * D_;

    const u32x4v onesu = {0x3F803F80u, 0x3F803F80u, 0x3F803F80u, 0x3F803F80u};
    const bf16x8 onesf = __builtin_bit_cast(bf16x8, onesu);

    bf16x8 qf[2][2];
#pragma unroll
    for (int t = 0; t < 2; t++) {
        const unsigned short* qrow =
            qkv + ((size_t)(b * T_ + q0s[t] + wave * 16 + c)) * RS + h * D_ + quad * 8;
        qf[t][0] = __builtin_bit_cast(bf16x8, *(const us8*)qrow);
        qf[t][1] = __builtin_bit_cast(bf16x8, *(const us8*)(qrow + 32));
    }

    const int kr0 = tid >> 3, kc0 = tid & 7;
    const int sK0 = sigmaK(kr0) * 72 + kc0 * 8;
    const int sK1 = sigmaK(kr0 + 32) * 72 + kc0 * 8;
    const int dg  = tid >> 4, kp0 = tid & 15;

    us8 kA, kB;
    ushort4 vA0, vB0, vA1, vB1;
    {
        kA = *(const us8*)(kbase + (size_t)kr0 * RS + kc0 * 8);
        kB = *(const us8*)(kbase + (size_t)(kr0 + 32) * RS + kc0 * 8);
        const unsigned short* p0 = vbase + (size_t)(2 * kp0) * RS + dg * 4;
        vA0 = *(const ushort4*)p0;  vB0 = *(const ushort4*)(p0 + RS);
        const unsigned short* p1 = vbase + (size_t)(2 * (kp0 + 16)) * RS + dg * 4;
        vA1 = *(const ushort4*)p1;  vB1 = *(const ushort4*)(p1 + RS);
    }

    f32x4 Oa[2][4];
    f32x4 Ol[2];
#pragma unroll
    for (int t = 0; t < 2; t++) {
        Ol[t] = (f32x4){0.f, 0.f, 0.f, 0.f};
#pragma unroll
        for (int d = 0; d < 4; d++) Oa[t][d] = (f32x4){0.f, 0.f, 0.f, 0.f};
    }

    const int ktEnd = qts[1];
    for (int kt = 0; kt <= ktEnd; kt++) {
        __syncthreads();
        *(us8*)&Ks[sK0] = kA;
        *(us8*)&Ks[sK1] = kB;
        {
            unsigned int* v0 = &Vt[(dg * 4) * 36 + kp0];
            v0[0]   = vA0.x | ((unsigned)vB0.x << 16);
            v0[36]  = vA0.y | ((unsigned)vB0.y << 16);
            v0[72]  = vA0.z | ((unsigned)vB0.z << 16);
            v0[108] = vA0.w | ((unsigned)vB0.w << 16);
            unsigned int* v1 = v0 + 16;
            v1[0]   = vA1.x | ((unsigned)vB1.x << 16);
            v1[36]  = vA1.y | ((unsigned)vB1.y << 16);
            v1[72]  = vA1.z | ((unsigned)vB1.z << 16);
            v1[108] = vA1.w | ((unsigned)vB1.w << 16);
        }
        __syncthreads();

        if (kt < ktEnd) {
            const unsigned short* kp = kbase + (size_t)((kt + 1) * 64) * RS;
            kA = *(const us8*)(kp + (size_t)kr0 * RS + kc0 * 8);
            kB = *(const us8*)(kp + (size_t)(kr0 + 32) * RS + kc0 * 8);
            const unsigned short* vp = vbase + (size_t)((kt + 1) * 64) * RS;
            const unsigned short* p0 = vp + (size_t)(2 * kp0) * RS + dg * 4;
            vA0 = *(const ushort4*)p0;  vB0 = *(const ushort4*)(p0 + RS);
            const unsigned short* p1 = vp + (size_t)(2 * (kp0 + 16)) * RS + dg * 4;
            vA1 = *(const ushort4*)p1;  vB1 = *(const ushort4*)(p1 + RS);
        }

        bf16x8 kf[4][2];
#pragma unroll
        for (int nb = 0; nb < 4; nb++) {
#pragma unroll
            for (int ks = 0; ks < 2; ks++)
                kf[nb][ks] = __builtin_bit_cast(bf16x8,
                    *(const us8*)&Ks[(nb * 16 + c) * 72 + quad * 8 + ks * 32]);
        }

#pragma unroll
        for (int t = 0; t < 2; t++) {
            if (kt > qts[t]) continue;
            const bool diag = (kt == qts[t]);
            const bool doHi = !diag || (wave >= 2);
            const int nbmax = diag ? ((wave >= 2) ? 3 : 1) : 3;

            f32x4 sv[4];
#pragma unroll
            for (int nb = 0; nb < 4; nb++) {
                if (nb <= nbmax) {
                    f32x4 z = (f32x4){0.f, 0.f, 0.f, 0.f};
                    z = __builtin_amdgcn_mfma_f32_16x16x32_bf16(kf[nb][0], qf[t][0], z, 0, 0, 0);
                    sv[nb] = __builtin_amdgcn_mfma_f32_16x16x32_bf16(kf[nb][1], qf[t][1], z, 0, 0, 0);
                }
            }
            if (diag) {
                const int qloc = wave * 16 + c;
#pragma unroll
                for (int nb = 0; nb < 4; nb++) {
                    if (nb <= nbmax) {
                        const int kb = 32 * (nb >> 1) + 4 * (nb & 1) + 8 * quad;
#pragma unroll
                        for (int r = 0; r < 4; r++)
                            if (kb + r > qloc) sv[nb][r] = -INFINITY;
                    }
                }
            }

            unsigned int pd[4][2];
#pragma unroll
            for (int nb = 0; nb < 4; nb++) {
                if (nb <= nbmax) {
                    float p0 = __builtin_amdgcn_exp2f(sv[nb][0]);
                    float p1 = __builtin_amdgcn_exp2f(sv[nb][1]);
                    float p2 = __builtin_amdgcn_exp2f(sv[nb][2]);
                    float p3 = __builtin_amdgcn_exp2f(sv[nb][3]);
                    unsigned u0 = __float_as_uint(p0) + 0x8000u;
                    unsigned u1 = __float_as_uint(p1) + 0x8000u;
                    unsigned u2 = __float_as_uint(p2) + 0x8000u;
                    unsigned u3 = __float_as_uint(p3) + 0x8000u;
                    pd[nb][0] = (u0 >> 16) | (u1 & 0xffff0000u);
                    pd[nb][1] = (u2 >> 16) | (u3 & 0xffff0000u);
                } else {
                    pd[nb][0] = 0u; pd[nb][1] = 0u;
                }
            }

            bf16x8 ap0 = __builtin_bit_cast(bf16x8,
                (u32x4v){pd[0][0], pd[0][1], pd[1][0], pd[1][1]});
            bf16x8 ap1 = __builtin_bit_cast(bf16x8,
                (u32x4v){pd[2][0], pd[2][1], pd[3][0], pd[3][1]});

            Ol[t] = __builtin_amdgcn_mfma_f32_16x16x32_bf16(ap0, onesf, Ol[t], 0, 0, 0);
            if (doHi)
                Ol[t] = __builtin_amdgcn_mfma_f32_16x16x32_bf16(ap1, onesf, Ol[t], 0, 0, 0);

#pragma unroll
            for (int dd = 0; dd < 4; dd++) {
                const unsigned int* vrow = &Vt[(dd * 16 + c) * 36 + quad * 4];
                bf16x8 vb0 = __builtin_bit_cast(bf16x8, *(const u32x4v*)vrow);
                Oa[t][dd] = __builtin_amdgcn_mfma_f32_16x16x32_bf16(ap0, vb0, Oa[t][dd], 0, 0, 0);
                if (doHi) {
                    bf16x8 vb1 = __builtin_bit_cast(bf16x8, *(const u32x4v*)(vrow + 16));
                    Oa[t][dd] = __builtin_amdgcn_mfma_f32_16x16x32_bf16(ap1, vb1, Oa[t][dd], 0, 0, 0);
                }
            }
        }
    }

#pragma unroll
    for (int t = 0; t < 2; t++) {
        unsigned short* yrow =
            y + ((size_t)(b * T_ + q0s[t] + wave * 16)) * C_ + h * D_;
#pragma unroll
        for (int r = 0; r < 4; r++) {
            float inv = 1.f / Ol[t][r];
#pragma unroll
            for (int dd = 0; dd < 4; dd++)
                yrow[(size_t)(quad * 4 + r) * C_ + dd * 16 + c] = f2bf(Oa[t][dd][r] * inv);
        }
    }
}

extern "C" void kernel_launch(void* const* d_in, const int* in_sizes, int n_in,
                              void* d_out, int out_size, void* d_ws, size_t ws_size,
                              hipStream_t stream) {
    const float* x      = (const float*)d_in[0];
    const float* w_qkv  = (const float*)d_in[1];
    const float* b_qkv  = (const float*)d_in[2];
    const float* w_proj = (const float*)d_in[3];
    const float* b_proj = (const float*)d_in[4];
    float* out = (float*)d_out;

    unsigned short* wqT  = (unsigned short*)d_ws;                 // [2304][768]
    unsigned short* wpT  = wqT  + (size_t)3 * C_ * C_;            // [768][768]
    unsigned short* qkvb = wpT  + (size_t)C_ * C_;                // [8192][2304]
    unsigned short* yb   = qkvb + (size_t)B_ * T_ * 3 * C_;       // [8192][768]
    float*          bqs  = (float*)(yb + (size_t)B_ * T_ * C_);   // [2304]

    prep_w<<<577, 256, 0, stream>>>(w_qkv, b_qkv, w_proj, wqT, wpT, bqs);

    // qkv = x @ w_qkv + b_qkv  (fp32 A converted in staging; bf16 out)
    gemm_pipe<1, 1><<<dim3(B_ * T_ / 128, 3 * C_ / 128), 256, 0, stream>>>(
        x, nullptr, wqT, bqs, qkvb, B_ * T_, 3 * C_, C_);

    // flash attention -> y (bf16)
    attn_mfma<<<8 * B_ * H_, 256, 0, stream>>>(qkvb, yb);

    // out = y @ w_proj + b_proj (bf16 A; fp32 out)
    gemm_pipe<0, 0><<<dim3(B_ * T_ / 128, C_ / 128), 256, 0, stream>>>(
        nullptr, yb, wpT, b_proj, out, B_ * T_, C_, C_);
}